// Round 1
// baseline (6537.276 us; speedup 1.0000x reference)
//
#include <hip/hip_runtime.h>
#include <hip/hip_bf16.h>
#include <math.h>

#define L_TOT 1024
#define HD 256

// Generic f32 GEMM: C[b, C_off+i, :] = A[b, A_off+i, :] @ W,  for i in [0,La), b in [0,4)
// A row address   = (b*A_Ls + A_off + i)*K       (A is K-wide, row-major)
// C row address   = (b*C_Ls + C_off + i)*ldc + n0
// gemm row m in [0, 4*La): b = m/La, i = m%La. 64x64 tile, BK=16, 4x4 per thread.
__global__ __launch_bounds__(256) void gemm_f32_kernel(
    const float* __restrict__ A, const float* __restrict__ W, float* __restrict__ C,
    int La, int K, int N, int A_Ls, int A_off, int C_Ls, int C_off, int ldc)
{
  __shared__ float As[16][65];   // +1 pad: kills the 16-way store conflict
  __shared__ float Ws[16][65];
  const int tid = threadIdx.x;
  const int m0 = blockIdx.y * 64;
  const int n0 = blockIdx.x * 64;
  const int tx = tid & 15, ty = tid >> 4;

  const int a_k  = tid & 15;          // k-slot for A staging
  const int a_i0 = (tid >> 4) * 4;    // 4 rows per thread
  const int w_n  = tid & 63;          // col for W staging
  const int w_k0 = (tid >> 6) * 4;    // 4 k's per thread

  const float* Arow[4];
#pragma unroll
  for (int r = 0; r < 4; ++r) {
    int m = m0 + a_i0 + r;
    int b = m / La, i = m - b * La;
    Arow[r] = A + (size_t)(b * A_Ls + A_off + i) * K;
  }

  float acc[4][4];
#pragma unroll
  for (int ii = 0; ii < 4; ++ii)
#pragma unroll
    for (int jj = 0; jj < 4; ++jj) acc[ii][jj] = 0.f;

  for (int kk = 0; kk < K; kk += 16) {
#pragma unroll
    for (int r = 0; r < 4; ++r) As[a_k][a_i0 + r] = Arow[r][kk + a_k];
#pragma unroll
    for (int r = 0; r < 4; ++r)
      Ws[w_k0 + r][w_n] = W[(size_t)(kk + w_k0 + r) * N + n0 + w_n];
    __syncthreads();
#pragma unroll
    for (int k = 0; k < 16; ++k) {
      float a[4], bb[4];
#pragma unroll
      for (int ii = 0; ii < 4; ++ii) a[ii] = As[k][ty * 4 + ii];     // ds_read_b128
#pragma unroll
      for (int jj = 0; jj < 4; ++jj) bb[jj] = Ws[k][tx * 4 + jj];    // ds_read_b128
#pragma unroll
      for (int ii = 0; ii < 4; ++ii)
#pragma unroll
        for (int jj = 0; jj < 4; ++jj) acc[ii][jj] += a[ii] * bb[jj];
    }
    __syncthreads();
  }

#pragma unroll
  for (int ii = 0; ii < 4; ++ii) {
    int m = m0 + ty * 4 + ii;
    int b = m / La, i = m - b * La;
    float* Cp = C + (size_t)(b * C_Ls + C_off + i) * ldc + n0 + tx * 4;
#pragma unroll
    for (int jj = 0; jj < 4; ++jj) Cp[jj] = acc[ii][jj];
  }
}

// In-place Gemma half-split RoPE on x laid out (B, 1024, NH, 256).
// One thread per (b,l,h,j), j<128: handles the (j, j+128) pair.
__global__ __launch_bounds__(256) void rope_kernel(
    float* __restrict__ x, const int* __restrict__ pos, int NH, int total)
{
  int idx = blockIdx.x * 256 + threadIdx.x;
  if (idx >= total) return;
  int j = idx & 127;
  int t = idx >> 7;          // b*1024*NH + l*NH + h
  int h = t % NH;
  int bl = t / NH;           // b*1024 + l
  int b = bl >> 10;
  int l = bl & (L_TOT - 1);
  float p = (float)pos[b * L_TOT + l];
  // inv_freq = 10000^(-j/128) = exp(-j * ln(10000)/128)
  float f = p * expf(-(float)j * (9.210340371976184f / 128.f));
  float s, c;
  sincosf(f, &s, &c);        // precise: args reach ~8191 rad
  size_t base = ((size_t)bl * NH + h) * HD;
  float x1 = x[base + j], x2 = x[base + 128 + j];
  x[base + j]       = x1 * c - x2 * s;
  x[base + 128 + j] = x2 * c + x1 * s;
}

// Flash-style attention, 1 KV head shared by 8 Q heads.
// Block = (b, h, 32-query tile); 256 threads; online softmax over 16 K-tiles of 64.
__global__ __launch_bounds__(256) void attn_kernel(
    const float* __restrict__ Q, const float* __restrict__ Kb, const float* __restrict__ Vb,
    const float* __restrict__ mask, float* __restrict__ O)
{
  const int qt = blockIdx.x;   // 0..31
  const int h  = blockIdx.y;   // 0..7
  const int b  = blockIdx.z;   // 0..3
  const int tid = threadIdx.x;

  __shared__ float Qs[32][HD + 1];   // pad: (qi+d)%32 banks, conflict-free
  __shared__ float Ss[32][65];
  __shared__ float mrow[32], lrow[32], arow[32];

  const int q0 = qt * 32;
  for (int x = tid; x < 32 * HD; x += 256) {
    int i = x >> 8, d = x & 255;
    Qs[i][d] = Q[(size_t)(b * L_TOT + q0 + i) * 2048 + h * HD + d];
  }
  if (tid < 32) { mrow[tid] = -1e30f; lrow[tid] = 0.f; }

  float Oacc[32];
#pragma unroll
  for (int j = 0; j < 32; ++j) Oacc[j] = 0.f;
  const int oq  = tid >> 3;          // O-owner query row
  const int od0 = (tid & 7) * 32;    // O-owner dim range [od0, od0+32)
  const int qi  = tid & 31;          // score-phase query row
  const int ks  = tid >> 5;          // score-phase k-slot (0..7)
  const float scale = 0.0625f;       // 1/sqrt(256)
  __syncthreads();

  for (int kt = 0; kt < L_TOT; kt += 64) {
    // --- scores: each thread does 8 dots of length 256 (float4 K loads) ---
#pragma unroll
    for (int j = 0; j < 8; ++j) {
      int kk = kt + ks + 8 * j;
      const float4* Kp = (const float4*)(Kb + (size_t)(b * L_TOT + kk) * HD);
      float s = 0.f;
      for (int d4 = 0; d4 < HD / 4; ++d4) {
        float4 kv = Kp[d4];
        s += Qs[qi][d4 * 4 + 0] * kv.x + Qs[qi][d4 * 4 + 1] * kv.y
           + Qs[qi][d4 * 4 + 2] * kv.z + Qs[qi][d4 * 4 + 3] * kv.w;
      }
      Ss[qi][ks + 8 * j] = s * scale
          + mask[(size_t)b * L_TOT * L_TOT + (size_t)(q0 + qi) * L_TOT + kk];
    }
    __syncthreads();
    // --- online softmax update (one thread per query row) ---
    if (tid < 32) {
      float m_old = mrow[tid];
      float mx = m_old;
#pragma unroll
      for (int k = 0; k < 64; ++k) mx = fmaxf(mx, Ss[tid][k]);
      float alpha = __expf(m_old - mx);
      float sum = 0.f;
#pragma unroll
      for (int k = 0; k < 64; ++k) {
        float pv = __expf(Ss[tid][k] - mx);
        Ss[tid][k] = pv;
        sum += pv;
      }
      lrow[tid] = lrow[tid] * alpha + sum;
      mrow[tid] = mx;
      arow[tid] = alpha;
    }
    __syncthreads();
    // --- O += P @ V (float4 V loads, coalesced across 8 dim-lanes) ---
    float alpha = arow[oq];
#pragma unroll
    for (int j = 0; j < 32; ++j) Oacc[j] *= alpha;
    for (int k = 0; k < 64; ++k) {
      float pv = Ss[oq][k];
      const float4* Vp = (const float4*)(Vb + (size_t)(b * L_TOT + kt + k) * HD + od0);
#pragma unroll
      for (int j4 = 0; j4 < 8; ++j4) {
        float4 vv = Vp[j4];
        Oacc[j4 * 4 + 0] += pv * vv.x;
        Oacc[j4 * 4 + 1] += pv * vv.y;
        Oacc[j4 * 4 + 2] += pv * vv.z;
        Oacc[j4 * 4 + 3] += pv * vv.w;
      }
    }
    __syncthreads();
  }
  float invl = 1.f / lrow[oq];
  float4* Op = (float4*)(O + (size_t)(b * L_TOT + q0 + oq) * 2048 + h * HD + od0);
#pragma unroll
  for (int j4 = 0; j4 < 8; ++j4) {
    float4 o;
    o.x = Oacc[j4 * 4 + 0] * invl;
    o.y = Oacc[j4 * 4 + 1] * invl;
    o.z = Oacc[j4 * 4 + 2] * invl;
    o.w = Oacc[j4 * 4 + 3] * invl;
    Op[j4] = o;
  }
}

extern "C" void kernel_launch(void* const* d_in, const int* in_sizes, int n_in,
                              void* d_out, int out_size, void* d_ws, size_t ws_size,
                              hipStream_t stream) {
  const float* pali = (const float*)d_in[0];
  const float* expe = (const float*)d_in[1];
  const int*   pos  = (const int*)d_in[2];
  const float* mask = (const float*)d_in[3];
  // d_in[4] = use_cache (always 0 here)
  const float* wq_p = (const float*)d_in[5];
  const float* wk_p = (const float*)d_in[6];
  const float* wv_p = (const float*)d_in[7];
  const float* wo_p = (const float*)d_in[8];
  const float* wq_e = (const float*)d_in[9];
  const float* wk_e = (const float*)d_in[10];
  const float* wv_e = (const float*)d_in[11];
  const float* wo_e = (const float*)d_in[12];
  float* out = (float*)d_out;

  // Workspace layout (f32): Q (4,1024,2048) | K (4,1024,256) | V | attn_out (4,1024,2048)
  float* Qbuf = (float*)d_ws;
  float* Kbuf = Qbuf + (size_t)4 * 1024 * 2048;
  float* Vbuf = Kbuf + (size_t)4 * 1024 * 256;
  float* Abuf = Vbuf + (size_t)4 * 1024 * 256;

  dim3 blk(256);
  // QKV projections (La, K, N, A_Ls, A_off, C_Ls, C_off, ldc)
  gemm_f32_kernel<<<dim3(2048/64, 3072/64), blk, 0, stream>>>(pali, wq_p, Qbuf, 768, 2048, 2048, 768, 0, 1024,   0, 2048);
  gemm_f32_kernel<<<dim3(2048/64, 1024/64), blk, 0, stream>>>(expe, wq_e, Qbuf, 256, 1024, 2048, 256, 0, 1024, 768, 2048);
  gemm_f32_kernel<<<dim3( 256/64, 3072/64), blk, 0, stream>>>(pali, wk_p, Kbuf, 768, 2048,  256, 768, 0, 1024,   0,  256);
  gemm_f32_kernel<<<dim3( 256/64, 1024/64), blk, 0, stream>>>(expe, wk_e, Kbuf, 256, 1024,  256, 256, 0, 1024, 768,  256);
  gemm_f32_kernel<<<dim3( 256/64, 3072/64), blk, 0, stream>>>(pali, wv_p, Vbuf, 768, 2048,  256, 768, 0, 1024,   0,  256);
  gemm_f32_kernel<<<dim3( 256/64, 1024/64), blk, 0, stream>>>(expe, wv_e, Vbuf, 256, 1024,  256, 256, 0, 1024, 768,  256);
  // RoPE (in place)
  rope_kernel<<<(4 * 1024 * 8 * 128 + 255) / 256, blk, 0, stream>>>(Qbuf, pos, 8, 4 * 1024 * 8 * 128);
  rope_kernel<<<(4 * 1024 * 1 * 128 + 255) / 256, blk, 0, stream>>>(Kbuf, pos, 1, 4 * 1024 * 1 * 128);
  // Attention
  attn_kernel<<<dim3(32, 8, 4), blk, 0, stream>>>(Qbuf, Kbuf, Vbuf, mask, Abuf);
  // Output projections
  gemm_f32_kernel<<<dim3(2048/64, 3072/64), blk, 0, stream>>>(Abuf, wo_p, out,                          768, 2048, 2048, 1024,   0,  768, 0, 2048);
  gemm_f32_kernel<<<dim3(1024/64, 1024/64), blk, 0, stream>>>(Abuf, wo_e, out + (size_t)4 * 768 * 2048, 256, 2048, 1024, 1024, 768,  256, 0, 1024);
}

// Round 2
// 2247.014 us; speedup vs baseline: 2.9093x; 2.9093x over previous
//
#include <hip/hip_runtime.h>
#include <hip/hip_bf16.h>
#include <math.h>

#define L_TOT 1024
#define HD 256

typedef __bf16 bf16x8 __attribute__((ext_vector_type(8)));
typedef float f32x4 __attribute__((ext_vector_type(4)));

// Generic f32 GEMM: C[b, C_off+i, :] = A[b, A_off+i, :] @ W,  for i in [0,La), b in [0,4)
__global__ __launch_bounds__(256) void gemm_f32_kernel(
    const float* __restrict__ A, const float* __restrict__ W, float* __restrict__ C,
    int La, int K, int N, int A_Ls, int A_off, int C_Ls, int C_off, int ldc)
{
  __shared__ float As[16][65];
  __shared__ float Ws[16][65];
  const int tid = threadIdx.x;
  const int m0 = blockIdx.y * 64;
  const int n0 = blockIdx.x * 64;
  const int tx = tid & 15, ty = tid >> 4;

  const int a_k  = tid & 15;
  const int a_i0 = (tid >> 4) * 4;
  const int w_n  = tid & 63;
  const int w_k0 = (tid >> 6) * 4;

  const float* Arow[4];
#pragma unroll
  for (int r = 0; r < 4; ++r) {
    int m = m0 + a_i0 + r;
    int b = m / La, i = m - b * La;
    Arow[r] = A + (size_t)(b * A_Ls + A_off + i) * K;
  }

  float acc[4][4];
#pragma unroll
  for (int ii = 0; ii < 4; ++ii)
#pragma unroll
    for (int jj = 0; jj < 4; ++jj) acc[ii][jj] = 0.f;

  for (int kk = 0; kk < K; kk += 16) {
#pragma unroll
    for (int r = 0; r < 4; ++r) As[a_k][a_i0 + r] = Arow[r][kk + a_k];
#pragma unroll
    for (int r = 0; r < 4; ++r)
      Ws[w_k0 + r][w_n] = W[(size_t)(kk + w_k0 + r) * N + n0 + w_n];
    __syncthreads();
#pragma unroll
    for (int k = 0; k < 16; ++k) {
      float a[4], bb[4];
#pragma unroll
      for (int ii = 0; ii < 4; ++ii) a[ii] = As[k][ty * 4 + ii];
#pragma unroll
      for (int jj = 0; jj < 4; ++jj) bb[jj] = Ws[k][tx * 4 + jj];
#pragma unroll
      for (int ii = 0; ii < 4; ++ii)
#pragma unroll
        for (int jj = 0; jj < 4; ++jj) acc[ii][jj] += a[ii] * bb[jj];
    }
    __syncthreads();
  }

#pragma unroll
  for (int ii = 0; ii < 4; ++ii) {
    int m = m0 + ty * 4 + ii;
    int b = m / La, i = m - b * La;
    float* Cp = C + (size_t)(b * C_Ls + C_off + i) * ldc + n0 + tx * 4;
#pragma unroll
    for (int jj = 0; jj < 4; ++jj) Cp[jj] = acc[ii][jj];
  }
}

// In-place Gemma half-split RoPE on x laid out (B, 1024, NH, 256).
__global__ __launch_bounds__(256) void rope_kernel(
    float* __restrict__ x, const int* __restrict__ pos, int NH, int total)
{
  int idx = blockIdx.x * 256 + threadIdx.x;
  if (idx >= total) return;
  int j = idx & 127;
  int t = idx >> 7;
  int h = t % NH;
  int bl = t / NH;
  int b = bl >> 10;
  int l = bl & (L_TOT - 1);
  float p = (float)pos[b * L_TOT + l];
  float f = p * expf(-(float)j * (9.210340371976184f / 128.f));
  float s, c;
  sincosf(f, &s, &c);
  size_t base = ((size_t)bl * NH + h) * HD;
  float x1 = x[base + j], x2 = x[base + 128 + j];
  x[base + j]       = x1 * c - x2 * s;
  x[base + 128 + j] = x2 * c + x1 * s;
}

// f32 -> bf16 elementwise
__global__ __launch_bounds__(256) void f32_to_bf16_kernel(
    const float* __restrict__ in, __bf16* __restrict__ out, int n)
{
  int i = blockIdx.x * 256 + threadIdx.x;
  if (i < n) out[i] = (__bf16)in[i];
}

// V (B,L,HD) f32  ->  Vt (B,HD,L) bf16; t enumerates (b,d,l) so writes coalesce.
__global__ __launch_bounds__(256) void transpose_v_bf16_kernel(
    const float* __restrict__ V, __bf16* __restrict__ Vt)
{
  int t = blockIdx.x * 256 + threadIdx.x;      // 4*256*1024 total
  int l = t & 1023;
  int d = (t >> 10) & 255;
  int b = t >> 18;
  Vt[t] = (__bf16)V[((size_t)b * L_TOT + l) * HD + d];
}

// MFMA flash attention. 1 wave = 16 query rows; 4 waves/block (independent, no barriers).
// Q: f32 (B,1024,2048) post-RoPE. Kb: bf16 (B,1024,256) post-RoPE. Vt: bf16 (B,256,1024).
// mask: f32 (B,1024,1024). O: f32 (B,1024,2048).
__global__ __launch_bounds__(256) void attn_mfma_kernel(
    const float* __restrict__ Q, const __bf16* __restrict__ Kb,
    const __bf16* __restrict__ Vt, const float* __restrict__ mask,
    float* __restrict__ O)
{
  const int tid  = threadIdx.x;
  const int wave = tid >> 6, lane = tid & 63;
  const int m    = lane & 15, quad = lane >> 4;
  const int h = blockIdx.y, b = blockIdx.z;
  const int q0 = blockIdx.x * 64 + wave * 16;

  // Per-wave private P tile (C-layout -> A-layout round trip). 72 = 64 + 8 pad,
  // keeps row stride at 144 B (16B-aligned for ds_read_b128, odd bank shift).
  __shared__ __align__(16) __bf16 Ps[4][16][72];

  // ---- Q A-fragments, loaded once: A[m=lane&15][k=quad*8+j] ----
  bf16x8 qf[8];
  {
    const float* qrow = Q + ((size_t)(b * L_TOT + q0 + m) * 2048) + h * HD + quad * 8;
#pragma unroll
    for (int f = 0; f < 8; ++f) {
      const float4* p = (const float4*)(qrow + f * 32);
      float4 lo = p[0], hi = p[1];
      bf16x8 v;
      v[0] = (__bf16)lo.x; v[1] = (__bf16)lo.y; v[2] = (__bf16)lo.z; v[3] = (__bf16)lo.w;
      v[4] = (__bf16)hi.x; v[5] = (__bf16)hi.y; v[6] = (__bf16)hi.z; v[7] = (__bf16)hi.w;
      qf[f] = v;
    }
  }

  // per-lane base pointers (B-operand: n = lane&15, k = quad*8+j, 16B contiguous)
  const __bf16* kl = Kb + ((size_t)(b * L_TOT) + m) * HD + quad * 8;
  const __bf16* vl = Vt + ((size_t)(b * HD) + m) * L_TOT + quad * 8;
  const float*  mk = mask + (size_t)b * L_TOT * L_TOT + (size_t)(q0 + quad * 4) * L_TOT + m;

  f32x4 Oacc[16];
#pragma unroll
  for (int i = 0; i < 16; ++i) Oacc[i] = (f32x4){0.f, 0.f, 0.f, 0.f};
  float mrow[4] = {-1e30f, -1e30f, -1e30f, -1e30f};
  float lrow[4] = {0.f, 0.f, 0.f, 0.f};

  for (int kt = 0; kt < L_TOT; kt += 64) {
    // ---- S = Q K^T : 4 col-blocks x 8 k-frags ----
    f32x4 S[4];
#pragma unroll
    for (int nb = 0; nb < 4; ++nb) {
      f32x4 s = (f32x4){0.f, 0.f, 0.f, 0.f};
      const __bf16* kp = kl + (size_t)(kt + nb * 16) * HD;
#pragma unroll
      for (int kf = 0; kf < 8; ++kf) {
        bf16x8 kfrag = *(const bf16x8*)(kp + kf * 32);
        s = __builtin_amdgcn_mfma_f32_16x16x32_bf16(qf[kf], kfrag, s, 0, 0, 0);
      }
      S[nb] = s;
    }
    // ---- scale + mask (C layout: row = quad*4+r, col = nb*16 + m) ----
#pragma unroll
    for (int nb = 0; nb < 4; ++nb)
#pragma unroll
      for (int r = 0; r < 4; ++r)
        S[nb][r] = S[nb][r] * 0.0625f + mk[(size_t)r * L_TOT + kt + nb * 16];
    // ---- online softmax: per-lane partial over 4 col-blocks, quad shuffle-reduce ----
    float mx[4];
#pragma unroll
    for (int r = 0; r < 4; ++r)
      mx[r] = fmaxf(fmaxf(S[0][r], S[1][r]), fmaxf(S[2][r], S[3][r]));
#pragma unroll
    for (int off = 1; off < 16; off <<= 1)
#pragma unroll
      for (int r = 0; r < 4; ++r)
        mx[r] = fmaxf(mx[r], __shfl_xor(mx[r], off, 64));
    float al[4];
#pragma unroll
    for (int r = 0; r < 4; ++r) {
      float mn = fmaxf(mrow[r], mx[r]);
      al[r] = __expf(mrow[r] - mn);
      mrow[r] = mn;
    }
    float rs[4] = {0.f, 0.f, 0.f, 0.f};
#pragma unroll
    for (int nb = 0; nb < 4; ++nb)
#pragma unroll
      for (int r = 0; r < 4; ++r) {
        float p = __expf(S[nb][r] - mrow[r]);
        rs[r] += p;
        Ps[wave][quad * 4 + r][nb * 16 + m] = (__bf16)p;
      }
#pragma unroll
    for (int off = 1; off < 16; off <<= 1)
#pragma unroll
      for (int r = 0; r < 4; ++r)
        rs[r] += __shfl_xor(rs[r], off, 64);
#pragma unroll
    for (int r = 0; r < 4; ++r) lrow[r] = lrow[r] * al[r] + rs[r];
    // ---- rescale O by alpha (alpha uniform across quad lanes) ----
#pragma unroll
    for (int nb2 = 0; nb2 < 16; ++nb2)
#pragma unroll
      for (int r = 0; r < 4; ++r) Oacc[nb2][r] *= al[r];
    // ---- O += P V : P back from LDS as A-frags; V B-frags from global Vt ----
    bf16x8 pf0 = *(const bf16x8*)&Ps[wave][m][quad * 8];
    bf16x8 pf1 = *(const bf16x8*)&Ps[wave][m][32 + quad * 8];
    const __bf16* vp = vl + kt;
#pragma unroll
    for (int nb2 = 0; nb2 < 16; ++nb2) {
      bf16x8 v0 = *(const bf16x8*)(vp + (size_t)nb2 * 16 * L_TOT);
      bf16x8 v1 = *(const bf16x8*)(vp + (size_t)nb2 * 16 * L_TOT + 32);
      Oacc[nb2] = __builtin_amdgcn_mfma_f32_16x16x32_bf16(pf0, v0, Oacc[nb2], 0, 0, 0);
      Oacc[nb2] = __builtin_amdgcn_mfma_f32_16x16x32_bf16(pf1, v1, Oacc[nb2], 0, 0, 0);
    }
  }
  // ---- epilogue: normalize, store (C layout) ----
  float invl[4];
#pragma unroll
  for (int r = 0; r < 4; ++r) invl[r] = 1.f / lrow[r];
  float* orow = O + ((size_t)(b * L_TOT + q0 + quad * 4) * 2048) + h * HD + m;
#pragma unroll
  for (int nb2 = 0; nb2 < 16; ++nb2)
#pragma unroll
    for (int r = 0; r < 4; ++r)
      orow[(size_t)r * 2048 + nb2 * 16] = Oacc[nb2][r] * invl[r];
}

extern "C" void kernel_launch(void* const* d_in, const int* in_sizes, int n_in,
                              void* d_out, int out_size, void* d_ws, size_t ws_size,
                              hipStream_t stream) {
  const float* pali = (const float*)d_in[0];
  const float* expe = (const float*)d_in[1];
  const int*   pos  = (const int*)d_in[2];
  const float* mask = (const float*)d_in[3];
  const float* wq_p = (const float*)d_in[5];
  const float* wk_p = (const float*)d_in[6];
  const float* wv_p = (const float*)d_in[7];
  const float* wo_p = (const float*)d_in[8];
  const float* wq_e = (const float*)d_in[9];
  const float* wk_e = (const float*)d_in[10];
  const float* wv_e = (const float*)d_in[11];
  const float* wo_e = (const float*)d_in[12];
  float* out = (float*)d_out;

  // Workspace: Q f32 (4,1024,2048) | K f32 | V f32 | attn_out f32 | K bf16 | Vt bf16
  float* Qbuf = (float*)d_ws;
  float* Kbuf = Qbuf + (size_t)4 * 1024 * 2048;
  float* Vbuf = Kbuf + (size_t)4 * 1024 * 256;
  float* Abuf = Vbuf + (size_t)4 * 1024 * 256;
  __bf16* Kb  = (__bf16*)(Abuf + (size_t)4 * 1024 * 2048);
  __bf16* Vt  = Kb + (size_t)4 * 1024 * 256;

  dim3 blk(256);
  // QKV projections
  gemm_f32_kernel<<<dim3(2048/64, 3072/64), blk, 0, stream>>>(pali, wq_p, Qbuf, 768, 2048, 2048, 768, 0, 1024,   0, 2048);
  gemm_f32_kernel<<<dim3(2048/64, 1024/64), blk, 0, stream>>>(expe, wq_e, Qbuf, 256, 1024, 2048, 256, 0, 1024, 768, 2048);
  gemm_f32_kernel<<<dim3( 256/64, 3072/64), blk, 0, stream>>>(pali, wk_p, Kbuf, 768, 2048,  256, 768, 0, 1024,   0,  256);
  gemm_f32_kernel<<<dim3( 256/64, 1024/64), blk, 0, stream>>>(expe, wk_e, Kbuf, 256, 1024,  256, 256, 0, 1024, 768,  256);
  gemm_f32_kernel<<<dim3( 256/64, 3072/64), blk, 0, stream>>>(pali, wv_p, Vbuf, 768, 2048,  256, 768, 0, 1024,   0,  256);
  gemm_f32_kernel<<<dim3( 256/64, 1024/64), blk, 0, stream>>>(expe, wv_e, Vbuf, 256, 1024,  256, 256, 0, 1024, 768,  256);
  // RoPE (in place, f32)
  rope_kernel<<<(4 * 1024 * 8 * 128 + 255) / 256, blk, 0, stream>>>(Qbuf, pos, 8, 4 * 1024 * 8 * 128);
  rope_kernel<<<(4 * 1024 * 1 * 128 + 255) / 256, blk, 0, stream>>>(Kbuf, pos, 1, 4 * 1024 * 1 * 128);
  // bf16 conversions for MFMA attention
  f32_to_bf16_kernel<<<(4 * 1024 * 256 + 255) / 256, blk, 0, stream>>>(Kbuf, Kb, 4 * 1024 * 256);
  transpose_v_bf16_kernel<<<(4 * 256 * 1024 + 255) / 256, blk, 0, stream>>>(Vbuf, Vt);
  // MFMA flash attention
  attn_mfma_kernel<<<dim3(16, 8, 4), blk, 0, stream>>>(Qbuf, Kb, Vt, mask, Abuf);
  // Output projections
  gemm_f32_kernel<<<dim3(2048/64, 3072/64), blk, 0, stream>>>(Abuf, wo_p, out,                          768, 2048, 2048, 1024,   0,  768, 0, 2048);
  gemm_f32_kernel<<<dim3(1024/64, 1024/64), blk, 0, stream>>>(Abuf, wo_e, out + (size_t)4 * 768 * 2048, 256, 2048, 1024, 1024, 768,  256, 0, 1024);
}

// Round 3
// 680.171 us; speedup vs baseline: 9.6112x; 3.3036x over previous
//
#include <hip/hip_runtime.h>
#include <hip/hip_bf16.h>
#include <math.h>

#define L_TOT 1024
#define HD 256
#define LDQKV 2560   // fused Q|K|V row width: 2048 Q + 256 K + 256 V

typedef __bf16 bf16x8 __attribute__((ext_vector_type(8)));
typedef __bf16 bf16x4 __attribute__((ext_vector_type(4)));
typedef float f32x4 __attribute__((ext_vector_type(4)));

__device__ __forceinline__ void gld_lds16(const __bf16* g, __bf16* l) {
  __builtin_amdgcn_global_load_lds(
      (const __attribute__((address_space(1))) void*)g,
      (__attribute__((address_space(3))) void*)l, 16, 0, 0);
}

// ---------------- f32 -> bf16 (vectorized x4) ----------------
__global__ __launch_bounds__(256) void cvt_bf16x4_kernel(
    const float* __restrict__ in, __bf16* __restrict__ out, int n4)
{
  int i = blockIdx.x * 256 + threadIdx.x;
  if (i >= n4) return;
  float4 v = ((const float4*)in)[i];
  bf16x4 o;
  o[0] = (__bf16)v.x; o[1] = (__bf16)v.y; o[2] = (__bf16)v.z; o[3] = (__bf16)v.w;
  ((bf16x4*)out)[i] = o;
}

// ---------------- weight transpose: W (K x N, f32) -> Wt (N x K, bf16) ----------------
// Wt base may be offset into a fused buffer (row offset pre-applied by caller).
__global__ __launch_bounds__(256) void transpose_w_kernel(
    const float* __restrict__ W, __bf16* __restrict__ Wt, int K, int N)
{
  __shared__ float t[32][33];
  const int n0 = blockIdx.x * 32, k0 = blockIdx.y * 32;
  const int tx = threadIdx.x & 31, ty = threadIdx.x >> 5;  // ty 0..7
#pragma unroll
  for (int r = 0; r < 32; r += 8)
    t[ty + r][tx] = W[(size_t)(k0 + ty + r) * N + n0 + tx];
  __syncthreads();
#pragma unroll
  for (int r = 0; r < 32; r += 8)
    Wt[(size_t)(n0 + ty + r) * K + k0 + tx] = (__bf16)t[tx][ty + r];
}

// ---------------- bf16 MFMA GEMM (m97 structure) ----------------
// C[b, C_off+i, n0..] = A[b, A_off+i, :] @ Wt^T     (Wt is N x K, K-contig)
// logical row m in [0, 4*La): b = m/La, i = m%La.
// 128x128 tile, BK=32, 4 waves, each wave 64x64 via 4x4 MFMA 16x16x32.
__global__ __launch_bounds__(256) void gemm_bf16_kernel(
    const __bf16* __restrict__ A, const __bf16* __restrict__ Wt, float* __restrict__ C,
    int La, int K, int A_Ls, int A_off, int C_Ls, int C_off, int ldc)
{
  __shared__ __bf16 As[128 * 32];
  __shared__ __bf16 Bs[128 * 32];
  const int tid = threadIdx.x;
  const int wave = tid >> 6, lane = tid & 63;
  const int m0 = blockIdx.y * 128, n0 = blockIdx.x * 128;
  const int lrow = lane >> 2;      // staged row within a wave-instr (0..15)
  const int k8   = lane & 3;       // 8-element k-group

  // staging global pointers (row constant over K-loop)
  const __bf16 *ag0, *ag1;
  {
    int m_a0 = m0 + wave * 16 + lrow;
    int m_a1 = m_a0 + 64;
    int b0 = m_a0 / La, b1 = m_a1 / La;
    ag0 = A + (size_t)(b0 * A_Ls + A_off + m_a0 - b0 * La) * K + k8 * 8;
    ag1 = A + (size_t)(b1 * A_Ls + A_off + m_a1 - b1 * La) * K + k8 * 8;
  }
  const __bf16* bg0 = Wt + (size_t)(n0 + wave * 16 + lrow) * K + k8 * 8;
  const __bf16* bg1 = bg0 + (size_t)64 * K;
  // per-wave uniform LDS bases (slot layout == [row][k] row-major, 32 elems/row)
  __bf16* al0 = As + wave * 512;
  __bf16* al1 = As + (4 + wave) * 512;
  __bf16* bl0 = Bs + wave * 512;
  __bf16* bl1 = Bs + (4 + wave) * 512;

  const int wm = (wave & 1) * 64, wn = (wave >> 1) * 64;
  const int fr = lane & 15, quad = lane >> 4;

  f32x4 acc[4][4];
#pragma unroll
  for (int i = 0; i < 4; ++i)
#pragma unroll
    for (int j = 0; j < 4; ++j) acc[i][j] = (f32x4){0.f, 0.f, 0.f, 0.f};

  for (int kk = 0; kk < K; kk += 32) {
    gld_lds16(ag0 + kk, al0);
    gld_lds16(ag1 + kk, al1);
    gld_lds16(bg0 + kk, bl0);
    gld_lds16(bg1 + kk, bl1);
    __syncthreads();
    bf16x8 af[4], bfr[4];
#pragma unroll
    for (int mt = 0; mt < 4; ++mt)
      af[mt] = *(const bf16x8*)(As + (wm + mt * 16 + fr) * 32 + quad * 8);
#pragma unroll
    for (int nt = 0; nt < 4; ++nt)
      bfr[nt] = *(const bf16x8*)(Bs + (wn + nt * 16 + fr) * 32 + quad * 8);
#pragma unroll
    for (int mt = 0; mt < 4; ++mt)
#pragma unroll
      for (int nt = 0; nt < 4; ++nt)
        acc[mt][nt] = __builtin_amdgcn_mfma_f32_16x16x32_bf16(af[mt], bfr[nt], acc[mt][nt], 0, 0, 0);
    __syncthreads();
  }

  // epilogue: C layout col=lane&15, row=quad*4+r
#pragma unroll
  for (int mt = 0; mt < 4; ++mt) {
#pragma unroll
    for (int r = 0; r < 4; ++r) {
      int m = m0 + wm + mt * 16 + quad * 4 + r;
      int b = m / La;
      float* crow = C + (size_t)(b * C_Ls + C_off + m - b * La) * ldc + n0 + wn + fr;
#pragma unroll
      for (int nt = 0; nt < 4; ++nt) crow[nt * 16] = acc[mt][nt][r];
    }
  }
}

// ---------------- RoPE in place on fused QKV f32 buffer ----------------
// x rows are (b*1024+l)*LDQKV; head h at col_off + h*256; pair (j, j+128).
__global__ __launch_bounds__(256) void rope_kernel(
    float* __restrict__ x, const int* __restrict__ pos, int NH, int col_off, int total)
{
  int idx = blockIdx.x * 256 + threadIdx.x;
  if (idx >= total) return;
  int j = idx & 127;
  int t = idx >> 7;
  int h = t % NH;
  int bl = t / NH;
  int b = bl >> 10;
  int l = bl & (L_TOT - 1);
  float p = (float)pos[b * L_TOT + l];
  float f = p * expf(-(float)j * (9.210340371976184f / 128.f));
  float s, c;
  sincosf(f, &s, &c);
  size_t base = (size_t)bl * LDQKV + col_off + h * HD;
  float x1 = x[base + j], x2 = x[base + 128 + j];
  x[base + j]       = x1 * c - x2 * s;
  x[base + 128 + j] = x2 * c + x1 * s;
}

// K columns of QKV (post-RoPE) -> Kb bf16 (B,1024,256)
__global__ __launch_bounds__(256) void cvt_k_kernel(
    const float* __restrict__ QKV, __bf16* __restrict__ Kb)
{
  int i = blockIdx.x * 256 + threadIdx.x;   // 4*1024*256
  int d = i & 255, bl = i >> 8;
  Kb[i] = (__bf16)QKV[(size_t)bl * LDQKV + 2048 + d];
}

// V columns of QKV -> Vt bf16 (B,256,1024), LDS-tiled transpose
__global__ __launch_bounds__(256) void transpose_v_kernel(
    const float* __restrict__ QKV, __bf16* __restrict__ Vt)
{
  __shared__ float t[32][33];
  const int b = blockIdx.z, d0 = blockIdx.x * 32, l0 = blockIdx.y * 32;
  const int tx = threadIdx.x & 31, ty = threadIdx.x >> 5;
#pragma unroll
  for (int r = 0; r < 32; r += 8)
    t[ty + r][tx] = QKV[(size_t)(b * L_TOT + l0 + ty + r) * LDQKV + 2304 + d0 + tx];
  __syncthreads();
#pragma unroll
  for (int r = 0; r < 32; r += 8)
    Vt[(size_t)(b * HD + d0 + ty + r) * L_TOT + l0 + tx] = (__bf16)t[tx][ty + r];
}

// ---------------- MFMA flash attention ----------------
// Q: f32 cols of fused QKV (ld LDQKV). Kb: bf16 (B,1024,256). Vt: bf16 (B,256,1024).
// mask: f32. O: bf16 (B,1024,2048) — feeds out-projection GEMMs directly.
__global__ __launch_bounds__(256) void attn_mfma_kernel(
    const float* __restrict__ QKV, const __bf16* __restrict__ Kb,
    const __bf16* __restrict__ Vt, const float* __restrict__ mask,
    __bf16* __restrict__ O)
{
  const int tid  = threadIdx.x;
  const int wave = tid >> 6, lane = tid & 63;
  const int m    = lane & 15, quad = lane >> 4;
  const int h = blockIdx.y, b = blockIdx.z;
  const int q0 = blockIdx.x * 64 + wave * 16;

  __shared__ __align__(16) __bf16 Ps[4][16][72];

  // Q A-fragments: A[m=lane&15][k=quad*8+j]
  bf16x8 qf[8];
  {
    const float* qrow = QKV + (size_t)(b * L_TOT + q0 + m) * LDQKV + h * HD + quad * 8;
#pragma unroll
    for (int f = 0; f < 8; ++f) {
      const float4* p = (const float4*)(qrow + f * 32);
      float4 lo = p[0], hi = p[1];
      bf16x8 v;
      v[0] = (__bf16)lo.x; v[1] = (__bf16)lo.y; v[2] = (__bf16)lo.z; v[3] = (__bf16)lo.w;
      v[4] = (__bf16)hi.x; v[5] = (__bf16)hi.y; v[6] = (__bf16)hi.z; v[7] = (__bf16)hi.w;
      qf[f] = v;
    }
  }

  const __bf16* kl = Kb + ((size_t)(b * L_TOT) + m) * HD + quad * 8;
  const __bf16* vl = Vt + ((size_t)(b * HD) + m) * L_TOT + quad * 8;
  const float*  mk = mask + (size_t)b * L_TOT * L_TOT + (size_t)(q0 + quad * 4) * L_TOT + m;

  f32x4 Oacc[16];
#pragma unroll
  for (int i = 0; i < 16; ++i) Oacc[i] = (f32x4){0.f, 0.f, 0.f, 0.f};
  float mrow[4] = {-1e30f, -1e30f, -1e30f, -1e30f};
  float lrow[4] = {0.f, 0.f, 0.f, 0.f};

  for (int kt = 0; kt < L_TOT; kt += 64) {
    f32x4 S[4];
#pragma unroll
    for (int nb = 0; nb < 4; ++nb) {
      f32x4 s = (f32x4){0.f, 0.f, 0.f, 0.f};
      const __bf16* kp = kl + (size_t)(kt + nb * 16) * HD;
#pragma unroll
      for (int kf = 0; kf < 8; ++kf) {
        bf16x8 kfrag = *(const bf16x8*)(kp + kf * 32);
        s = __builtin_amdgcn_mfma_f32_16x16x32_bf16(qf[kf], kfrag, s, 0, 0, 0);
      }
      S[nb] = s;
    }
#pragma unroll
    for (int nb = 0; nb < 4; ++nb)
#pragma unroll
      for (int r = 0; r < 4; ++r)
        S[nb][r] = S[nb][r] * 0.0625f + mk[(size_t)r * L_TOT + kt + nb * 16];
    float mx[4];
#pragma unroll
    for (int r = 0; r < 4; ++r)
      mx[r] = fmaxf(fmaxf(S[0][r], S[1][r]), fmaxf(S[2][r], S[3][r]));
#pragma unroll
    for (int off = 1; off < 16; off <<= 1)
#pragma unroll
      for (int r = 0; r < 4; ++r)
        mx[r] = fmaxf(mx[r], __shfl_xor(mx[r], off, 64));
    float al[4];
#pragma unroll
    for (int r = 0; r < 4; ++r) {
      float mn = fmaxf(mrow[r], mx[r]);
      al[r] = __expf(mrow[r] - mn);
      mrow[r] = mn;
    }
    float rs[4] = {0.f, 0.f, 0.f, 0.f};
#pragma unroll
    for (int nb = 0; nb < 4; ++nb)
#pragma unroll
      for (int r = 0; r < 4; ++r) {
        float p = __expf(S[nb][r] - mrow[r]);
        rs[r] += p;
        Ps[wave][quad * 4 + r][nb * 16 + m] = (__bf16)p;
      }
#pragma unroll
    for (int off = 1; off < 16; off <<= 1)
#pragma unroll
      for (int r = 0; r < 4; ++r)
        rs[r] += __shfl_xor(rs[r], off, 64);
#pragma unroll
    for (int r = 0; r < 4; ++r) lrow[r] = lrow[r] * al[r] + rs[r];
#pragma unroll
    for (int nb2 = 0; nb2 < 16; ++nb2)
#pragma unroll
      for (int r = 0; r < 4; ++r) Oacc[nb2][r] *= al[r];
    bf16x8 pf0 = *(const bf16x8*)&Ps[wave][m][quad * 8];
    bf16x8 pf1 = *(const bf16x8*)&Ps[wave][m][32 + quad * 8];
    const __bf16* vp = vl + kt;
#pragma unroll
    for (int nb2 = 0; nb2 < 16; ++nb2) {
      bf16x8 v0 = *(const bf16x8*)(vp + (size_t)nb2 * 16 * L_TOT);
      bf16x8 v1 = *(const bf16x8*)(vp + (size_t)nb2 * 16 * L_TOT + 32);
      Oacc[nb2] = __builtin_amdgcn_mfma_f32_16x16x32_bf16(pf0, v0, Oacc[nb2], 0, 0, 0);
      Oacc[nb2] = __builtin_amdgcn_mfma_f32_16x16x32_bf16(pf1, v1, Oacc[nb2], 0, 0, 0);
    }
  }
  float invl[4];
#pragma unroll
  for (int r = 0; r < 4; ++r) invl[r] = 1.f / lrow[r];
  __bf16* orow = O + (size_t)(b * L_TOT + q0 + quad * 4) * 2048 + h * HD + m;
#pragma unroll
  for (int nb2 = 0; nb2 < 16; ++nb2)
#pragma unroll
    for (int r = 0; r < 4; ++r)
      orow[(size_t)r * 2048 + nb2 * 16] = (__bf16)(Oacc[nb2][r] * invl[r]);
}

extern "C" void kernel_launch(void* const* d_in, const int* in_sizes, int n_in,
                              void* d_out, int out_size, void* d_ws, size_t ws_size,
                              hipStream_t stream) {
  const float* pali = (const float*)d_in[0];
  const float* expe = (const float*)d_in[1];
  const int*   pos  = (const int*)d_in[2];
  const float* mask = (const float*)d_in[3];
  const float* wq_p = (const float*)d_in[5];
  const float* wk_p = (const float*)d_in[6];
  const float* wv_p = (const float*)d_in[7];
  const float* wo_p = (const float*)d_in[8];
  const float* wq_e = (const float*)d_in[9];
  const float* wk_e = (const float*)d_in[10];
  const float* wv_e = (const float*)d_in[11];
  const float* wo_e = (const float*)d_in[12];
  float* out = (float*)d_out;

  // Workspace layout
  float*  QKV    = (float*)d_ws;                              // 4*1024*2560 f32
  __bf16* Ab     = (__bf16*)(QKV + (size_t)4 * 1024 * 2560);  // 4*1024*2048 bf16
  __bf16* palib  = Ab + (size_t)4 * 1024 * 2048;              // 4*768*2048
  __bf16* expeb  = palib + (size_t)4 * 768 * 2048;            // 4*256*1024
  __bf16* Kb     = expeb + (size_t)4 * 256 * 1024;            // 4*1024*256
  __bf16* Vt     = Kb + (size_t)4 * 1024 * 256;               // 4*256*1024
  __bf16* WqkvpT = Vt + (size_t)4 * 256 * 1024;               // 2560*2048
  __bf16* WqkveT = WqkvpT + (size_t)2560 * 2048;              // 2560*1024
  __bf16* WopT   = WqkveT + (size_t)2560 * 1024;              // 2048*2048
  __bf16* WoeT   = WopT + (size_t)2048 * 2048;                // 1024*2048

  dim3 blk(256);
  // activation conversions
  cvt_bf16x4_kernel<<<(4 * 768 * 2048 / 4 + 255) / 256, blk, 0, stream>>>(pali, palib, 4 * 768 * 2048 / 4);
  cvt_bf16x4_kernel<<<(4 * 256 * 1024 / 4 + 255) / 256, blk, 0, stream>>>(expe, expeb, 4 * 256 * 1024 / 4);
  // weight transposes into fused QKV^T buffers
  transpose_w_kernel<<<dim3(2048/32, 2048/32), blk, 0, stream>>>(wq_p, WqkvpT,                         2048, 2048);
  transpose_w_kernel<<<dim3( 256/32, 2048/32), blk, 0, stream>>>(wk_p, WqkvpT + (size_t)2048 * 2048,   2048,  256);
  transpose_w_kernel<<<dim3( 256/32, 2048/32), blk, 0, stream>>>(wv_p, WqkvpT + (size_t)2304 * 2048,   2048,  256);
  transpose_w_kernel<<<dim3(2048/32, 1024/32), blk, 0, stream>>>(wq_e, WqkveT,                         1024, 2048);
  transpose_w_kernel<<<dim3( 256/32, 1024/32), blk, 0, stream>>>(wk_e, WqkveT + (size_t)2048 * 1024,   1024,  256);
  transpose_w_kernel<<<dim3( 256/32, 1024/32), blk, 0, stream>>>(wv_e, WqkveT + (size_t)2304 * 1024,   1024,  256);
  transpose_w_kernel<<<dim3(2048/32, 2048/32), blk, 0, stream>>>(wo_p, WopT,                           2048, 2048);
  transpose_w_kernel<<<dim3(1024/32, 2048/32), blk, 0, stream>>>(wo_e, WoeT,                           2048, 1024);
  // fused QKV projections (f32 out)
  gemm_bf16_kernel<<<dim3(2560/128, 3072/128), blk, 0, stream>>>(palib, WqkvpT, QKV, 768, 2048, 768, 0, 1024,   0, LDQKV);
  gemm_bf16_kernel<<<dim3(2560/128, 1024/128), blk, 0, stream>>>(expeb, WqkveT, QKV, 256, 1024, 256, 0, 1024, 768, LDQKV);
  // RoPE in place (Q heads, then K)
  rope_kernel<<<(4 * 1024 * 8 * 128 + 255) / 256, blk, 0, stream>>>(QKV, pos, 8,    0, 4 * 1024 * 8 * 128);
  rope_kernel<<<(4 * 1024 * 1 * 128 + 255) / 256, blk, 0, stream>>>(QKV, pos, 1, 2048, 4 * 1024 * 1 * 128);
  // K/V bf16 prep
  cvt_k_kernel<<<(4 * 1024 * 256 + 255) / 256, blk, 0, stream>>>(QKV, Kb);
  transpose_v_kernel<<<dim3(8, 32, 4), blk, 0, stream>>>(QKV, Vt);
  // attention (bf16 out -> Ab)
  attn_mfma_kernel<<<dim3(16, 8, 4), blk, 0, stream>>>(QKV, Kb, Vt, mask, Ab);
  // output projections
  gemm_bf16_kernel<<<dim3(2048/128, 3072/128), blk, 0, stream>>>(Ab, WopT, out,                          768, 2048, 1024,   0, 768, 0, 2048);
  gemm_bf16_kernel<<<dim3(1024/128, 1024/128), blk, 0, stream>>>(Ab, WoeT, out + (size_t)4 * 768 * 2048, 256, 2048, 1024, 768, 256, 0, 1024);
}

// Round 4
// 537.271 us; speedup vs baseline: 12.1675x; 1.2660x over previous
//
#include <hip/hip_runtime.h>
#include <hip/hip_bf16.h>
#include <math.h>

#define L_TOT 1024
#define HD 256
#define LDQKV 2560   // fused Q|K|V row width: 2048 Q + 256 K + 256 V

typedef __bf16 bf16x8 __attribute__((ext_vector_type(8)));
typedef __bf16 bf16x4 __attribute__((ext_vector_type(4)));
typedef float f32x4 __attribute__((ext_vector_type(4)));

__device__ __forceinline__ void gld_lds16(const __bf16* g, __bf16* l) {
  __builtin_amdgcn_global_load_lds(
      (const __attribute__((address_space(1))) void*)g,
      (__attribute__((address_space(3))) void*)l, 16, 0, 0);
}

// ---------------- f32 -> bf16 (vectorized x4) ----------------
__global__ __launch_bounds__(256) void cvt_bf16x4_kernel(
    const float* __restrict__ in, __bf16* __restrict__ out, int n4)
{
  int i = blockIdx.x * 256 + threadIdx.x;
  if (i >= n4) return;
  float4 v = ((const float4*)in)[i];
  bf16x4 o;
  o[0] = (__bf16)v.x; o[1] = (__bf16)v.y; o[2] = (__bf16)v.z; o[3] = (__bf16)v.w;
  ((bf16x4*)out)[i] = o;
}

// ---------------- weight transpose: W (K x N, f32) -> Wt (N x K, bf16) ----------------
__global__ __launch_bounds__(256) void transpose_w_kernel(
    const float* __restrict__ W, __bf16* __restrict__ Wt, int K, int N)
{
  __shared__ float t[32][33];
  const int n0 = blockIdx.x * 32, k0 = blockIdx.y * 32;
  const int tx = threadIdx.x & 31, ty = threadIdx.x >> 5;  // ty 0..7
#pragma unroll
  for (int r = 0; r < 32; r += 8)
    t[ty + r][tx] = W[(size_t)(k0 + ty + r) * N + n0 + tx];
  __syncthreads();
#pragma unroll
  for (int r = 0; r < 32; r += 8)
    Wt[(size_t)(n0 + ty + r) * K + k0 + tx] = (__bf16)t[tx][ty + r];
}

// ---------------- bf16 MFMA GEMM (m97 structure) ----------------
__global__ __launch_bounds__(256) void gemm_bf16_kernel(
    const __bf16* __restrict__ A, const __bf16* __restrict__ Wt, float* __restrict__ C,
    int La, int K, int A_Ls, int A_off, int C_Ls, int C_off, int ldc)
{
  __shared__ __bf16 As[128 * 32];
  __shared__ __bf16 Bs[128 * 32];
  const int tid = threadIdx.x;
  const int wave = tid >> 6, lane = tid & 63;
  const int m0 = blockIdx.y * 128, n0 = blockIdx.x * 128;
  const int lrow = lane >> 2;
  const int k8   = lane & 3;

  const __bf16 *ag0, *ag1;
  {
    int m_a0 = m0 + wave * 16 + lrow;
    int m_a1 = m_a0 + 64;
    int b0 = m_a0 / La, b1 = m_a1 / La;
    ag0 = A + (size_t)(b0 * A_Ls + A_off + m_a0 - b0 * La) * K + k8 * 8;
    ag1 = A + (size_t)(b1 * A_Ls + A_off + m_a1 - b1 * La) * K + k8 * 8;
  }
  const __bf16* bg0 = Wt + (size_t)(n0 + wave * 16 + lrow) * K + k8 * 8;
  const __bf16* bg1 = bg0 + (size_t)64 * K;
  __bf16* al0 = As + wave * 512;
  __bf16* al1 = As + (4 + wave) * 512;
  __bf16* bl0 = Bs + wave * 512;
  __bf16* bl1 = Bs + (4 + wave) * 512;

  const int wm = (wave & 1) * 64, wn = (wave >> 1) * 64;
  const int fr = lane & 15, quad = lane >> 4;

  f32x4 acc[4][4];
#pragma unroll
  for (int i = 0; i < 4; ++i)
#pragma unroll
    for (int j = 0; j < 4; ++j) acc[i][j] = (f32x4){0.f, 0.f, 0.f, 0.f};

  for (int kk = 0; kk < K; kk += 32) {
    gld_lds16(ag0 + kk, al0);
    gld_lds16(ag1 + kk, al1);
    gld_lds16(bg0 + kk, bl0);
    gld_lds16(bg1 + kk, bl1);
    __syncthreads();
    bf16x8 af[4], bfr[4];
#pragma unroll
    for (int mt = 0; mt < 4; ++mt)
      af[mt] = *(const bf16x8*)(As + (wm + mt * 16 + fr) * 32 + quad * 8);
#pragma unroll
    for (int nt = 0; nt < 4; ++nt)
      bfr[nt] = *(const bf16x8*)(Bs + (wn + nt * 16 + fr) * 32 + quad * 8);
#pragma unroll
    for (int mt = 0; mt < 4; ++mt)
#pragma unroll
      for (int nt = 0; nt < 4; ++nt)
        acc[mt][nt] = __builtin_amdgcn_mfma_f32_16x16x32_bf16(af[mt], bfr[nt], acc[mt][nt], 0, 0, 0);
    __syncthreads();
  }

#pragma unroll
  for (int mt = 0; mt < 4; ++mt) {
#pragma unroll
    for (int r = 0; r < 4; ++r) {
      int m = m0 + wm + mt * 16 + quad * 4 + r;
      int b = m / La;
      float* crow = C + (size_t)(b * C_Ls + C_off + m - b * La) * ldc + n0 + wn + fr;
#pragma unroll
      for (int nt = 0; nt < 4; ++nt) crow[nt * 16] = acc[mt][nt][r];
    }
  }
}

// ---------------- RoPE in place on fused QKV f32 buffer ----------------
__global__ __launch_bounds__(256) void rope_kernel(
    float* __restrict__ x, const int* __restrict__ pos, int NH, int col_off, int total)
{
  int idx = blockIdx.x * 256 + threadIdx.x;
  if (idx >= total) return;
  int j = idx & 127;
  int t = idx >> 7;
  int h = t % NH;
  int bl = t / NH;
  int b = bl >> 10;
  int l = bl & (L_TOT - 1);
  float p = (float)pos[b * L_TOT + l];
  float f = p * expf(-(float)j * (9.210340371976184f / 128.f));
  float s, c;
  sincosf(f, &s, &c);
  size_t base = (size_t)bl * LDQKV + col_off + h * HD;
  float x1 = x[base + j], x2 = x[base + 128 + j];
  x[base + j]       = x1 * c - x2 * s;
  x[base + 128 + j] = x2 * c + x1 * s;
}

// K columns of QKV (post-RoPE) -> Kb bf16 (B,1024,256)
__global__ __launch_bounds__(256) void cvt_k_kernel(
    const float* __restrict__ QKV, __bf16* __restrict__ Kb)
{
  int i = blockIdx.x * 256 + threadIdx.x;
  int d = i & 255, bl = i >> 8;
  Kb[i] = (__bf16)QKV[(size_t)bl * LDQKV + 2048 + d];
}

// V columns of QKV -> Vt bf16 (B,256,1024), LDS-tiled transpose
__global__ __launch_bounds__(256) void transpose_v_kernel(
    const float* __restrict__ QKV, __bf16* __restrict__ Vt)
{
  __shared__ float t[32][33];
  const int b = blockIdx.z, d0 = blockIdx.x * 32, l0 = blockIdx.y * 32;
  const int tx = threadIdx.x & 31, ty = threadIdx.x >> 5;
#pragma unroll
  for (int r = 0; r < 32; r += 8)
    t[ty + r][tx] = QKV[(size_t)(b * L_TOT + l0 + ty + r) * LDQKV + 2304 + d0 + tx];
  __syncthreads();
#pragma unroll
  for (int r = 0; r < 32; r += 8)
    Vt[(size_t)(b * HD + d0 + ty + r) * L_TOT + l0 + tx] = (__bf16)t[tx][ty + r];
}

// ---------------- MFMA flash attention, LDS-staged K/V tiles ----------------
// Block = (b, h, 64-q tile), 4 waves x 16 q-rows. Per kt-tile of 32 keys:
// K tile (32x256) and V tile (256x32) staged via async global_load_lds with
// rotation-swizzled layouts (coalesced global, conflict-free ds_read_b128).
__global__ __launch_bounds__(256) void attn_mfma_kernel(
    const float* __restrict__ QKV, const __bf16* __restrict__ Kb,
    const __bf16* __restrict__ Vt, const float* __restrict__ mask,
    __bf16* __restrict__ O)
{
  const int tid  = threadIdx.x;
  const int wave = tid >> 6, lane = tid & 63;
  const int m    = lane & 15, quad = lane >> 4;
  const int h = blockIdx.y, b = blockIdx.z;
  const int q0 = blockIdx.x * 64 + wave * 16;

  // Ks[key][dim] with 16B-group rotated by key: elem (key, g*8+j) at key*256 + ((g+key)&31)*8
  __shared__ __align__(16) __bf16 Ks[32 * 256];   // 16 KB
  // Vs[dim][key] with 16B-group rotated by (dim>>1)&3: elem (d, g*8+j) at d*32 + ((g+(d>>1))&3)*8
  __shared__ __align__(16) __bf16 Vs[256 * 32];   // 16 KB
  __shared__ __align__(16) __bf16 Ps[4][16][40];  // per-wave P tile, stride 40 conflict-free

  // ---- Q A-fragments (load once, f32 -> bf16): A[m][k=quad*8+j] ----
  bf16x8 qf[8];
  {
    const float* qrow = QKV + (size_t)(b * L_TOT + q0 + m) * LDQKV + h * HD + quad * 8;
#pragma unroll
    for (int f = 0; f < 8; ++f) {
      const float4* p = (const float4*)(qrow + f * 32);
      float4 lo = p[0], hi = p[1];
      bf16x8 v;
      v[0] = (__bf16)lo.x; v[1] = (__bf16)lo.y; v[2] = (__bf16)lo.z; v[3] = (__bf16)lo.w;
      v[4] = (__bf16)hi.x; v[5] = (__bf16)hi.y; v[6] = (__bf16)hi.z; v[7] = (__bf16)hi.w;
      qf[f] = v;
    }
  }

  // staging lane roles (constant over the loop)
  const int krow_l = lane >> 5;                    // 0/1: row within 2-row chunk
  const int kcol_l = ((lane & 31) * 8);            // base col elems before rotation
  const int vd_l   = lane >> 2;                    // 0..15: dim within 16-dim chunk
  const int vg_l   = lane & 3;                     // 16B group slot

  const float* mk = mask + (size_t)b * L_TOT * L_TOT + (size_t)(q0 + quad * 4) * L_TOT + m;

  f32x4 Oacc[16];
#pragma unroll
  for (int i = 0; i < 16; ++i) Oacc[i] = (f32x4){0.f, 0.f, 0.f, 0.f};
  float mrow[4] = {-1e30f, -1e30f, -1e30f, -1e30f};
  float lrow[4] = {0.f, 0.f, 0.f, 0.f};

  for (int kt = 0; kt < L_TOT; kt += 32) {
    // ---- stage K tile: 16 instrs of 1KB; wave does c = wave*4+i ----
#pragma unroll
    for (int i = 0; i < 4; ++i) {
      int c = wave * 4 + i;
      int r = 2 * c + krow_l;                              // local key 0..31
      int colg = ((lane & 31) - r) & 31;                   // rotated source group
      gld_lds16(Kb + ((size_t)(b * L_TOT + kt + r)) * HD + colg * 8, Ks + c * 512);
    }
    // ---- stage V tile ----
#pragma unroll
    for (int i = 0; i < 4; ++i) {
      int c = wave * 4 + i;
      int d = c * 16 + vd_l;                               // dim 0..255
      int gg = (vg_l - ((d >> 1) & 3)) & 3;                // rotated source group
      gld_lds16(Vt + ((size_t)(b * HD + d)) * L_TOT + kt + gg * 8, Vs + c * 512);
    }
    __syncthreads();

    // ---- S = Q K^T : 2 key-blocks of 16, 8 k-frags each (2 acc chains) ----
    f32x4 S[2];
#pragma unroll
    for (int nb = 0; nb < 2; ++nb) {
      int row = nb * 16 + m;
      f32x4 se = (f32x4){0.f, 0.f, 0.f, 0.f};
      f32x4 so = (f32x4){0.f, 0.f, 0.f, 0.f};
#pragma unroll
      for (int kf = 0; kf < 8; ++kf) {
        bf16x8 kf8 = *(const bf16x8*)(Ks + row * 256 + (((kf << 2) + quad + row) & 31) * 8);
        if (kf & 1) so = __builtin_amdgcn_mfma_f32_16x16x32_bf16(qf[kf], kf8, so, 0, 0, 0);
        else        se = __builtin_amdgcn_mfma_f32_16x16x32_bf16(qf[kf], kf8, se, 0, 0, 0);
      }
      S[nb] = se + so;
    }
    // ---- scale + mask (C layout: row=quad*4+r, col=nb*16+m) ----
#pragma unroll
    for (int nb = 0; nb < 2; ++nb)
#pragma unroll
      for (int r = 0; r < 4; ++r)
        S[nb][r] = S[nb][r] * 0.0625f + mk[(size_t)r * L_TOT + kt + nb * 16];
    // ---- online softmax ----
    float mx[4];
#pragma unroll
    for (int r = 0; r < 4; ++r) mx[r] = fmaxf(S[0][r], S[1][r]);
#pragma unroll
    for (int off = 1; off < 16; off <<= 1)
#pragma unroll
      for (int r = 0; r < 4; ++r)
        mx[r] = fmaxf(mx[r], __shfl_xor(mx[r], off, 64));
    float al[4];
#pragma unroll
    for (int r = 0; r < 4; ++r) {
      float mn = fmaxf(mrow[r], mx[r]);
      al[r] = __expf(mrow[r] - mn);
      mrow[r] = mn;
    }
    float rs[4] = {0.f, 0.f, 0.f, 0.f};
#pragma unroll
    for (int nb = 0; nb < 2; ++nb)
#pragma unroll
      for (int r = 0; r < 4; ++r) {
        float p = __expf(S[nb][r] - mrow[r]);
        rs[r] += p;
        Ps[wave][quad * 4 + r][nb * 16 + m] = (__bf16)p;
      }
#pragma unroll
    for (int off = 1; off < 16; off <<= 1)
#pragma unroll
      for (int r = 0; r < 4; ++r)
        rs[r] += __shfl_xor(rs[r], off, 64);
#pragma unroll
    for (int r = 0; r < 4; ++r) lrow[r] = lrow[r] * al[r] + rs[r];
#pragma unroll
    for (int nb2 = 0; nb2 < 16; ++nb2)
#pragma unroll
      for (int r = 0; r < 4; ++r) Oacc[nb2][r] *= al[r];
    // ---- O += P V ----
    bf16x8 pf = *(const bf16x8*)&Ps[wave][m][quad * 8];
#pragma unroll
    for (int nb2 = 0; nb2 < 16; ++nb2) {
      int d = nb2 * 16 + m;
      bf16x8 vfrag = *(const bf16x8*)(Vs + d * 32 + ((quad + ((d >> 1) & 3)) & 3) * 8);
      Oacc[nb2] = __builtin_amdgcn_mfma_f32_16x16x32_bf16(pf, vfrag, Oacc[nb2], 0, 0, 0);
    }
    __syncthreads();
  }
  // ---- epilogue ----
  float invl[4];
#pragma unroll
  for (int r = 0; r < 4; ++r) invl[r] = 1.f / lrow[r];
  __bf16* orow = O + (size_t)(b * L_TOT + q0 + quad * 4) * 2048 + h * HD + m;
#pragma unroll
  for (int nb2 = 0; nb2 < 16; ++nb2)
#pragma unroll
    for (int r = 0; r < 4; ++r)
      orow[(size_t)r * 2048 + nb2 * 16] = (__bf16)(Oacc[nb2][r] * invl[r]);
}

extern "C" void kernel_launch(void* const* d_in, const int* in_sizes, int n_in,
                              void* d_out, int out_size, void* d_ws, size_t ws_size,
                              hipStream_t stream) {
  const float* pali = (const float*)d_in[0];
  const float* expe = (const float*)d_in[1];
  const int*   pos  = (const int*)d_in[2];
  const float* mask = (const float*)d_in[3];
  const float* wq_p = (const float*)d_in[5];
  const float* wk_p = (const float*)d_in[6];
  const float* wv_p = (const float*)d_in[7];
  const float* wo_p = (const float*)d_in[8];
  const float* wq_e = (const float*)d_in[9];
  const float* wk_e = (const float*)d_in[10];
  const float* wv_e = (const float*)d_in[11];
  const float* wo_e = (const float*)d_in[12];
  float* out = (float*)d_out;

  float*  QKV    = (float*)d_ws;                              // 4*1024*2560 f32
  __bf16* Ab     = (__bf16*)(QKV + (size_t)4 * 1024 * 2560);  // 4*1024*2048 bf16
  __bf16* palib  = Ab + (size_t)4 * 1024 * 2048;              // 4*768*2048
  __bf16* expeb  = palib + (size_t)4 * 768 * 2048;            // 4*256*1024
  __bf16* Kb     = expeb + (size_t)4 * 256 * 1024;            // 4*1024*256
  __bf16* Vt     = Kb + (size_t)4 * 1024 * 256;               // 4*256*1024
  __bf16* WqkvpT = Vt + (size_t)4 * 256 * 1024;               // 2560*2048
  __bf16* WqkveT = WqkvpT + (size_t)2560 * 2048;              // 2560*1024
  __bf16* WopT   = WqkveT + (size_t)2560 * 1024;              // 2048*2048
  __bf16* WoeT   = WopT + (size_t)2048 * 2048;                // 1024*2048

  dim3 blk(256);
  cvt_bf16x4_kernel<<<(4 * 768 * 2048 / 4 + 255) / 256, blk, 0, stream>>>(pali, palib, 4 * 768 * 2048 / 4);
  cvt_bf16x4_kernel<<<(4 * 256 * 1024 / 4 + 255) / 256, blk, 0, stream>>>(expe, expeb, 4 * 256 * 1024 / 4);
  transpose_w_kernel<<<dim3(2048/32, 2048/32), blk, 0, stream>>>(wq_p, WqkvpT,                         2048, 2048);
  transpose_w_kernel<<<dim3( 256/32, 2048/32), blk, 0, stream>>>(wk_p, WqkvpT + (size_t)2048 * 2048,   2048,  256);
  transpose_w_kernel<<<dim3( 256/32, 2048/32), blk, 0, stream>>>(wv_p, WqkvpT + (size_t)2304 * 2048,   2048,  256);
  transpose_w_kernel<<<dim3(2048/32, 1024/32), blk, 0, stream>>>(wq_e, WqkveT,                         1024, 2048);
  transpose_w_kernel<<<dim3( 256/32, 1024/32), blk, 0, stream>>>(wk_e, WqkveT + (size_t)2048 * 1024,   1024,  256);
  transpose_w_kernel<<<dim3( 256/32, 1024/32), blk, 0, stream>>>(wv_e, WqkveT + (size_t)2304 * 1024,   1024,  256);
  transpose_w_kernel<<<dim3(2048/32, 2048/32), blk, 0, stream>>>(wo_p, WopT,                           2048, 2048);
  transpose_w_kernel<<<dim3(1024/32, 2048/32), blk, 0, stream>>>(wo_e, WoeT,                           2048, 1024);
  gemm_bf16_kernel<<<dim3(2560/128, 3072/128), blk, 0, stream>>>(palib, WqkvpT, QKV, 768, 2048, 768, 0, 1024,   0, LDQKV);
  gemm_bf16_kernel<<<dim3(2560/128, 1024/128), blk, 0, stream>>>(expeb, WqkveT, QKV, 256, 1024, 256, 0, 1024, 768, LDQKV);
  rope_kernel<<<(4 * 1024 * 8 * 128 + 255) / 256, blk, 0, stream>>>(QKV, pos, 8,    0, 4 * 1024 * 8 * 128);
  rope_kernel<<<(4 * 1024 * 1 * 128 + 255) / 256, blk, 0, stream>>>(QKV, pos, 1, 2048, 4 * 1024 * 1 * 128);
  cvt_k_kernel<<<(4 * 1024 * 256 + 255) / 256, blk, 0, stream>>>(QKV, Kb);
  transpose_v_kernel<<<dim3(8, 32, 4), blk, 0, stream>>>(QKV, Vt);
  attn_mfma_kernel<<<dim3(16, 8, 4), blk, 0, stream>>>(QKV, Kb, Vt, mask, Ab);
  gemm_bf16_kernel<<<dim3(2048/128, 3072/128), blk, 0, stream>>>(Ab, WopT, out,                          768, 2048, 1024,   0, 768, 0, 2048);
  gemm_bf16_kernel<<<dim3(1024/128, 1024/128), blk, 0, stream>>>(Ab, WoeT, out + (size_t)4 * 768 * 2048, 256, 2048, 1024, 768, 256, 0, 1024);
}

// Round 5
// 482.028 us; speedup vs baseline: 13.5620x; 1.1146x over previous
//
#include <hip/hip_runtime.h>
#include <hip/hip_bf16.h>
#include <math.h>

#define L_TOT 1024
#define HD 256
#define LDQKV 2560   // fused Q|K|V row width: 2048 Q + 256 K + 256 V

typedef __bf16 bf16x8 __attribute__((ext_vector_type(8)));
typedef __bf16 bf16x4 __attribute__((ext_vector_type(4)));
typedef float f32x4 __attribute__((ext_vector_type(4)));

__device__ __forceinline__ void gld_lds16(const __bf16* g, __bf16* l) {
  __builtin_amdgcn_global_load_lds(
      (const __attribute__((address_space(1))) void*)g,
      (__attribute__((address_space(3))) void*)l, 16, 0, 0);
}

// ---------------- f32 -> bf16 (vectorized x4) ----------------
__global__ __launch_bounds__(256) void cvt_bf16x4_kernel(
    const float* __restrict__ in, __bf16* __restrict__ out, int n4)
{
  int i = blockIdx.x * 256 + threadIdx.x;
  if (i >= n4) return;
  float4 v = ((const float4*)in)[i];
  bf16x4 o;
  o[0] = (__bf16)v.x; o[1] = (__bf16)v.y; o[2] = (__bf16)v.z; o[3] = (__bf16)v.w;
  ((bf16x4*)out)[i] = o;
}

// ---------------- weight transpose: W (K x N, f32) -> Wt (N x K, bf16) ----------------
__global__ __launch_bounds__(256) void transpose_w_kernel(
    const float* __restrict__ W, __bf16* __restrict__ Wt, int K, int N)
{
  __shared__ float t[32][33];
  const int n0 = blockIdx.x * 32, k0 = blockIdx.y * 32;
  const int tx = threadIdx.x & 31, ty = threadIdx.x >> 5;  // ty 0..7
#pragma unroll
  for (int r = 0; r < 32; r += 8)
    t[ty + r][tx] = W[(size_t)(k0 + ty + r) * N + n0 + tx];
  __syncthreads();
#pragma unroll
  for (int r = 0; r < 32; r += 8)
    Wt[(size_t)(n0 + ty + r) * K + k0 + tx] = (__bf16)t[tx][ty + r];
}

// ---------------- bf16 MFMA GEMM (m97 structure) ----------------
__global__ __launch_bounds__(256) void gemm_bf16_kernel(
    const __bf16* __restrict__ A, const __bf16* __restrict__ Wt, float* __restrict__ C,
    int La, int K, int A_Ls, int A_off, int C_Ls, int C_off, int ldc)
{
  __shared__ __bf16 As[128 * 32];
  __shared__ __bf16 Bs[128 * 32];
  const int tid = threadIdx.x;
  const int wave = tid >> 6, lane = tid & 63;
  const int m0 = blockIdx.y * 128, n0 = blockIdx.x * 128;
  const int lrow = lane >> 2;
  const int k8   = lane & 3;

  const __bf16 *ag0, *ag1;
  {
    int m_a0 = m0 + wave * 16 + lrow;
    int m_a1 = m_a0 + 64;
    int b0 = m_a0 / La, b1 = m_a1 / La;
    ag0 = A + (size_t)(b0 * A_Ls + A_off + m_a0 - b0 * La) * K + k8 * 8;
    ag1 = A + (size_t)(b1 * A_Ls + A_off + m_a1 - b1 * La) * K + k8 * 8;
  }
  const __bf16* bg0 = Wt + (size_t)(n0 + wave * 16 + lrow) * K + k8 * 8;
  const __bf16* bg1 = bg0 + (size_t)64 * K;
  __bf16* al0 = As + wave * 512;
  __bf16* al1 = As + (4 + wave) * 512;
  __bf16* bl0 = Bs + wave * 512;
  __bf16* bl1 = Bs + (4 + wave) * 512;

  const int wm = (wave & 1) * 64, wn = (wave >> 1) * 64;
  const int fr = lane & 15, quad = lane >> 4;

  f32x4 acc[4][4];
#pragma unroll
  for (int i = 0; i < 4; ++i)
#pragma unroll
    for (int j = 0; j < 4; ++j) acc[i][j] = (f32x4){0.f, 0.f, 0.f, 0.f};

  for (int kk = 0; kk < K; kk += 32) {
    gld_lds16(ag0 + kk, al0);
    gld_lds16(ag1 + kk, al1);
    gld_lds16(bg0 + kk, bl0);
    gld_lds16(bg1 + kk, bl1);
    __syncthreads();
    bf16x8 af[4], bfr[4];
#pragma unroll
    for (int mt = 0; mt < 4; ++mt)
      af[mt] = *(const bf16x8*)(As + (wm + mt * 16 + fr) * 32 + quad * 8);
#pragma unroll
    for (int nt = 0; nt < 4; ++nt)
      bfr[nt] = *(const bf16x8*)(Bs + (wn + nt * 16 + fr) * 32 + quad * 8);
#pragma unroll
    for (int mt = 0; mt < 4; ++mt)
#pragma unroll
      for (int nt = 0; nt < 4; ++nt)
        acc[mt][nt] = __builtin_amdgcn_mfma_f32_16x16x32_bf16(af[mt], bfr[nt], acc[mt][nt], 0, 0, 0);
    __syncthreads();
  }

#pragma unroll
  for (int mt = 0; mt < 4; ++mt) {
#pragma unroll
    for (int r = 0; r < 4; ++r) {
      int m = m0 + wm + mt * 16 + quad * 4 + r;
      int b = m / La;
      float* crow = C + (size_t)(b * C_Ls + C_off + m - b * La) * ldc + n0 + wn + fr;
#pragma unroll
      for (int nt = 0; nt < 4; ++nt) crow[nt * 16] = acc[mt][nt][r];
    }
  }
}

// ---------------- RoPE in place on fused QKV f32 buffer ----------------
__global__ __launch_bounds__(256) void rope_kernel(
    float* __restrict__ x, const int* __restrict__ pos, int NH, int col_off, int total)
{
  int idx = blockIdx.x * 256 + threadIdx.x;
  if (idx >= total) return;
  int j = idx & 127;
  int t = idx >> 7;
  int h = t % NH;
  int bl = t / NH;
  int b = bl >> 10;
  int l = bl & (L_TOT - 1);
  float p = (float)pos[b * L_TOT + l];
  float f = p * expf(-(float)j * (9.210340371976184f / 128.f));
  float s, c;
  sincosf(f, &s, &c);
  size_t base = (size_t)bl * LDQKV + col_off + h * HD;
  float x1 = x[base + j], x2 = x[base + 128 + j];
  x[base + j]       = x1 * c - x2 * s;
  x[base + 128 + j] = x2 * c + x1 * s;
}

// K columns of QKV (post-RoPE) -> Kb bf16 (B,1024,256)
__global__ __launch_bounds__(256) void cvt_k_kernel(
    const float* __restrict__ QKV, __bf16* __restrict__ Kb)
{
  int i = blockIdx.x * 256 + threadIdx.x;
  int d = i & 255, bl = i >> 8;
  Kb[i] = (__bf16)QKV[(size_t)bl * LDQKV + 2048 + d];
}

// V columns of QKV -> Vt bf16 (B,256,1024), LDS-tiled transpose
__global__ __launch_bounds__(256) void transpose_v_kernel(
    const float* __restrict__ QKV, __bf16* __restrict__ Vt)
{
  __shared__ float t[32][33];
  const int b = blockIdx.z, d0 = blockIdx.x * 32, l0 = blockIdx.y * 32;
  const int tx = threadIdx.x & 31, ty = threadIdx.x >> 5;
#pragma unroll
  for (int r = 0; r < 32; r += 8)
    t[ty + r][tx] = QKV[(size_t)(b * L_TOT + l0 + ty + r) * LDQKV + 2304 + d0 + tx];
  __syncthreads();
#pragma unroll
  for (int r = 0; r < 32; r += 8)
    Vt[(size_t)(b * HD + d0 + ty + r) * L_TOT + l0 + tx] = (__bf16)t[tx][ty + r];
}

// ---------------- MFMA flash attention, double-buffered LDS K/V tiles ----------------
// Block = (b, h, 64-q tile), 4 waves x 16 q-rows. 32-key tiles.
// Tile t+1 staged (async global_load_lds) during tile t's compute; ONE barrier
// per iteration, so the vmcnt(0) drain at the barrier waits on loads that had a
// full compute phase to land. Mask scalars for tile t+1 prefetched into VGPRs.
__global__ __launch_bounds__(256) void attn_mfma_kernel(
    const float* __restrict__ QKV, const __bf16* __restrict__ Kb,
    const __bf16* __restrict__ Vt, const float* __restrict__ mask,
    __bf16* __restrict__ O)
{
  const int tid  = threadIdx.x;
  const int wave = tid >> 6, lane = tid & 63;
  const int m    = lane & 15, quad = lane >> 4;
  const int h = blockIdx.y, b = blockIdx.z;
  const int q0 = blockIdx.x * 64 + wave * 16;

  // Ks[buf][key][dim]: 16B-group rotated by key (slot s holds source group (s-key)&31)
  __shared__ __align__(16) __bf16 Ks[2][32 * 256];   // 2 x 16 KB
  // Vs[buf][dim][key]: 16B-group rotated by (dim>>1)&3
  __shared__ __align__(16) __bf16 Vs[2][256 * 32];   // 2 x 16 KB
  __shared__ __align__(16) __bf16 Ps[4][16][40];     // per-wave P tile

  // ---- Q A-fragments (load once, f32 -> bf16): A[m][k=quad*8+j] ----
  bf16x8 qf[8];
  {
    const float* qrow = QKV + (size_t)(b * L_TOT + q0 + m) * LDQKV + h * HD + quad * 8;
#pragma unroll
    for (int f = 0; f < 8; ++f) {
      const float4* p = (const float4*)(qrow + f * 32);
      float4 lo = p[0], hi = p[1];
      bf16x8 v;
      v[0] = (__bf16)lo.x; v[1] = (__bf16)lo.y; v[2] = (__bf16)lo.z; v[3] = (__bf16)lo.w;
      v[4] = (__bf16)hi.x; v[5] = (__bf16)hi.y; v[6] = (__bf16)hi.z; v[7] = (__bf16)hi.w;
      qf[f] = v;
    }
  }

  // staging lane roles (constant over the loop)
  const int krow_l = lane >> 5;                    // 0/1: key within 2-key chunk
  const int vd_l   = lane >> 2;                    // 0..15: dim within 16-dim chunk
  const int vg_l   = lane & 3;                     // 16B group slot

  // per-lane staging source offsets for chunk c = wave*4+i (i=0..3)
  size_t ksrc[4], vsrc[4];
#pragma unroll
  for (int i = 0; i < 4; ++i) {
    int c = wave * 4 + i;
    int r = 2 * c + krow_l;
    int colg = ((lane & 31) - r) & 31;
    ksrc[i] = ((size_t)(b * L_TOT + r)) * HD + colg * 8;
    int d = c * 16 + vd_l;
    int gg = (vg_l - ((d >> 1) & 3)) & 3;
    vsrc[i] = ((size_t)(b * HD + d)) * L_TOT + gg * 8;
  }

  const float* mk = mask + (size_t)b * L_TOT * L_TOT + (size_t)(q0 + quad * 4) * L_TOT + m;

  f32x4 Oacc[16];
#pragma unroll
  for (int i = 0; i < 16; ++i) Oacc[i] = (f32x4){0.f, 0.f, 0.f, 0.f};
  float mrow[4] = {-1e30f, -1e30f, -1e30f, -1e30f};
  float lrow[4] = {0.f, 0.f, 0.f, 0.f};

  // ---- preload tile 0 into buf 0; prefetch tile-0 mask ----
#pragma unroll
  for (int i = 0; i < 4; ++i) {
    int c = wave * 4 + i;
    gld_lds16(Kb + ksrc[i], &Ks[0][c * 512]);
    gld_lds16(Vt + vsrc[i], &Vs[0][c * 512]);
  }
  float mcur[2][4];
#pragma unroll
  for (int nb = 0; nb < 2; ++nb)
#pragma unroll
    for (int r = 0; r < 4; ++r) mcur[nb][r] = mk[(size_t)r * L_TOT + nb * 16];

  for (int it = 0; it < 32; ++it) {
    const int kt = it * 32;
    const int buf = it & 1;
    __syncthreads();   // tile `it` staged; buf^1 free (prev iter's reads done)

    // ---- issue staging for tile it+1 into buf^1 (lands during compute) ----
    if (it + 1 < 32) {
#pragma unroll
      for (int i = 0; i < 4; ++i) {
        int c = wave * 4 + i;
        gld_lds16(Kb + ksrc[i] + (size_t)(kt + 32) * HD, &Ks[buf ^ 1][c * 512]);
        gld_lds16(Vt + vsrc[i] + (kt + 32), &Vs[buf ^ 1][c * 512]);
      }
    }
    // ---- prefetch next tile's mask into registers ----
    float mnext[2][4];
    if (it + 1 < 32) {
#pragma unroll
      for (int nb = 0; nb < 2; ++nb)
#pragma unroll
        for (int r = 0; r < 4; ++r)
          mnext[nb][r] = mk[(size_t)r * L_TOT + (kt + 32) + nb * 16];
    }

    // ---- S = Q K^T : 2 key-blocks of 16, 8 k-frags each (2 acc chains) ----
    f32x4 S[2];
#pragma unroll
    for (int nb = 0; nb < 2; ++nb) {
      int row = nb * 16 + m;
      f32x4 se = (f32x4){0.f, 0.f, 0.f, 0.f};
      f32x4 so = (f32x4){0.f, 0.f, 0.f, 0.f};
#pragma unroll
      for (int kf = 0; kf < 8; ++kf) {
        bf16x8 kf8 = *(const bf16x8*)(&Ks[buf][0] + row * 256 + (((kf << 2) + quad + row) & 31) * 8);
        if (kf & 1) so = __builtin_amdgcn_mfma_f32_16x16x32_bf16(qf[kf], kf8, so, 0, 0, 0);
        else        se = __builtin_amdgcn_mfma_f32_16x16x32_bf16(qf[kf], kf8, se, 0, 0, 0);
      }
      S[nb] = se + so;
    }
    // ---- scale + mask (C layout: row=quad*4+r, col=nb*16+m) ----
#pragma unroll
    for (int nb = 0; nb < 2; ++nb)
#pragma unroll
      for (int r = 0; r < 4; ++r)
        S[nb][r] = S[nb][r] * 0.0625f + mcur[nb][r];
    // ---- online softmax ----
    float mx[4];
#pragma unroll
    for (int r = 0; r < 4; ++r) mx[r] = fmaxf(S[0][r], S[1][r]);
#pragma unroll
    for (int off = 1; off < 16; off <<= 1)
#pragma unroll
      for (int r = 0; r < 4; ++r)
        mx[r] = fmaxf(mx[r], __shfl_xor(mx[r], off, 64));
    float al[4];
#pragma unroll
    for (int r = 0; r < 4; ++r) {
      float mn = fmaxf(mrow[r], mx[r]);
      al[r] = __expf(mrow[r] - mn);
      mrow[r] = mn;
    }
    float rs[4] = {0.f, 0.f, 0.f, 0.f};
#pragma unroll
    for (int nb = 0; nb < 2; ++nb)
#pragma unroll
      for (int r = 0; r < 4; ++r) {
        float p = __expf(S[nb][r] - mrow[r]);
        rs[r] += p;
        Ps[wave][quad * 4 + r][nb * 16 + m] = (__bf16)p;
      }
#pragma unroll
    for (int off = 1; off < 16; off <<= 1)
#pragma unroll
      for (int r = 0; r < 4; ++r)
        rs[r] += __shfl_xor(rs[r], off, 64);
#pragma unroll
    for (int r = 0; r < 4; ++r) lrow[r] = lrow[r] * al[r] + rs[r];
#pragma unroll
    for (int nb2 = 0; nb2 < 16; ++nb2)
#pragma unroll
      for (int r = 0; r < 4; ++r) Oacc[nb2][r] *= al[r];
    // ---- O += P V ----
    bf16x8 pf = *(const bf16x8*)&Ps[wave][m][quad * 8];
#pragma unroll
    for (int nb2 = 0; nb2 < 16; ++nb2) {
      int d = nb2 * 16 + m;
      bf16x8 vfrag = *(const bf16x8*)(&Vs[buf][0] + d * 32 + ((quad + ((d >> 1) & 3)) & 3) * 8);
      Oacc[nb2] = __builtin_amdgcn_mfma_f32_16x16x32_bf16(pf, vfrag, Oacc[nb2], 0, 0, 0);
    }
#pragma unroll
    for (int nb = 0; nb < 2; ++nb)
#pragma unroll
      for (int r = 0; r < 4; ++r) mcur[nb][r] = mnext[nb][r];
  }
  // ---- epilogue ----
  float invl[4];
#pragma unroll
  for (int r = 0; r < 4; ++r) invl[r] = 1.f / lrow[r];
  __bf16* orow = O + (size_t)(b * L_TOT + q0 + quad * 4) * 2048 + h * HD + m;
#pragma unroll
  for (int nb2 = 0; nb2 < 16; ++nb2)
#pragma unroll
    for (int r = 0; r < 4; ++r)
      orow[(size_t)r * 2048 + nb2 * 16] = (__bf16)(Oacc[nb2][r] * invl[r]);
}

extern "C" void kernel_launch(void* const* d_in, const int* in_sizes, int n_in,
                              void* d_out, int out_size, void* d_ws, size_t ws_size,
                              hipStream_t stream) {
  const float* pali = (const float*)d_in[0];
  const float* expe = (const float*)d_in[1];
  const int*   pos  = (const int*)d_in[2];
  const float* mask = (const float*)d_in[3];
  const float* wq_p = (const float*)d_in[5];
  const float* wk_p = (const float*)d_in[6];
  const float* wv_p = (const float*)d_in[7];
  const float* wo_p = (const float*)d_in[8];
  const float* wq_e = (const float*)d_in[9];
  const float* wk_e = (const float*)d_in[10];
  const float* wv_e = (const float*)d_in[11];
  const float* wo_e = (const float*)d_in[12];
  float* out = (float*)d_out;

  float*  QKV    = (float*)d_ws;                              // 4*1024*2560 f32
  __bf16* Ab     = (__bf16*)(QKV + (size_t)4 * 1024 * 2560);  // 4*1024*2048 bf16
  __bf16* palib  = Ab + (size_t)4 * 1024 * 2048;              // 4*768*2048
  __bf16* expeb  = palib + (size_t)4 * 768 * 2048;            // 4*256*1024
  __bf16* Kb     = expeb + (size_t)4 * 256 * 1024;            // 4*1024*256
  __bf16* Vt     = Kb + (size_t)4 * 1024 * 256;               // 4*256*1024
  __bf16* WqkvpT = Vt + (size_t)4 * 256 * 1024;               // 2560*2048
  __bf16* WqkveT = WqkvpT + (size_t)2560 * 2048;              // 2560*1024
  __bf16* WopT   = WqkveT + (size_t)2560 * 1024;              // 2048*2048
  __bf16* WoeT   = WopT + (size_t)2048 * 2048;                // 1024*2048

  dim3 blk(256);
  cvt_bf16x4_kernel<<<(4 * 768 * 2048 / 4 + 255) / 256, blk, 0, stream>>>(pali, palib, 4 * 768 * 2048 / 4);
  cvt_bf16x4_kernel<<<(4 * 256 * 1024 / 4 + 255) / 256, blk, 0, stream>>>(expe, expeb, 4 * 256 * 1024 / 4);
  transpose_w_kernel<<<dim3(2048/32, 2048/32), blk, 0, stream>>>(wq_p, WqkvpT,                         2048, 2048);
  transpose_w_kernel<<<dim3( 256/32, 2048/32), blk, 0, stream>>>(wk_p, WqkvpT + (size_t)2048 * 2048,   2048,  256);
  transpose_w_kernel<<<dim3( 256/32, 2048/32), blk, 0, stream>>>(wv_p, WqkvpT + (size_t)2304 * 2048,   2048,  256);
  transpose_w_kernel<<<dim3(2048/32, 1024/32), blk, 0, stream>>>(wq_e, WqkveT,                         1024, 2048);
  transpose_w_kernel<<<dim3( 256/32, 1024/32), blk, 0, stream>>>(wk_e, WqkveT + (size_t)2048 * 1024,   1024,  256);
  transpose_w_kernel<<<dim3( 256/32, 1024/32), blk, 0, stream>>>(wv_e, WqkveT + (size_t)2304 * 1024,   1024,  256);
  transpose_w_kernel<<<dim3(2048/32, 2048/32), blk, 0, stream>>>(wo_p, WopT,                           2048, 2048);
  transpose_w_kernel<<<dim3(1024/32, 2048/32), blk, 0, stream>>>(wo_e, WoeT,                           2048, 1024);
  gemm_bf16_kernel<<<dim3(2560/128, 3072/128), blk, 0, stream>>>(palib, WqkvpT, QKV, 768, 2048, 768, 0, 1024,   0, LDQKV);
  gemm_bf16_kernel<<<dim3(2560/128, 1024/128), blk, 0, stream>>>(expeb, WqkveT, QKV, 256, 1024, 256, 0, 1024, 768, LDQKV);
  rope_kernel<<<(4 * 1024 * 8 * 128 + 255) / 256, blk, 0, stream>>>(QKV, pos, 8,    0, 4 * 1024 * 8 * 128);
  rope_kernel<<<(4 * 1024 * 1 * 128 + 255) / 256, blk, 0, stream>>>(QKV, pos, 1, 2048, 4 * 1024 * 1 * 128);
  cvt_k_kernel<<<(4 * 1024 * 256 + 255) / 256, blk, 0, stream>>>(QKV, Kb);
  transpose_v_kernel<<<dim3(8, 32, 4), blk, 0, stream>>>(QKV, Vt);
  attn_mfma_kernel<<<dim3(16, 8, 4), blk, 0, stream>>>(QKV, Kb, Vt, mask, Ab);
  gemm_bf16_kernel<<<dim3(2048/128, 3072/128), blk, 0, stream>>>(Ab, WopT, out,                          768, 2048, 1024,   0, 768, 0, 2048);
  gemm_bf16_kernel<<<dim3(1024/128, 1024/128), blk, 0, stream>>>(Ab, WoeT, out + (size_t)4 * 768 * 2048, 256, 2048, 1024, 768, 256, 0, 1024);
}

// Round 6
// 399.109 us; speedup vs baseline: 16.3797x; 1.2078x over previous
//
#include <hip/hip_runtime.h>
#include <hip/hip_bf16.h>
#include <math.h>

#define L_TOT 1024
#define HD 256
#define LDQKV 2560   // fused Q|K|V row width (bf16): 2048 Q + 256 K + 256 V

typedef __bf16 bf16x8 __attribute__((ext_vector_type(8)));
typedef __bf16 bf16x4 __attribute__((ext_vector_type(4)));
typedef float f32x4 __attribute__((ext_vector_type(4)));

__device__ __forceinline__ void gld_lds16(const __bf16* g, __bf16* l) {
  __builtin_amdgcn_global_load_lds(
      (const __attribute__((address_space(1))) void*)g,
      (__attribute__((address_space(3))) void*)l, 16, 0, 0);
}

// ======================= PREP: all weight transposes + activation cvts =======================
__device__ __forceinline__ void do_cvt(const float* __restrict__ in, __bf16* __restrict__ out,
                                       int i) {
  float4 v = ((const float4*)in)[i];
  bf16x4 o;
  o[0] = (__bf16)v.x; o[1] = (__bf16)v.y; o[2] = (__bf16)v.z; o[3] = (__bf16)v.w;
  ((bf16x4*)out)[i] = o;
}

__device__ __forceinline__ void do_transpose(const float* __restrict__ W, __bf16* __restrict__ Wt,
                                             int K, int N, int rem, int tid, float (*t)[33]) {
  const int tiles_x = N >> 5;
  const int n0 = (rem % tiles_x) * 32, k0 = (rem / tiles_x) * 32;
  const int tx = tid & 31, ty = tid >> 5;  // ty 0..7
#pragma unroll
  for (int r = 0; r < 32; r += 8)
    t[ty + r][tx] = W[(size_t)(k0 + ty + r) * N + n0 + tx];
  __syncthreads();
#pragma unroll
  for (int r = 0; r < 32; r += 8)
    Wt[(size_t)(n0 + ty + r) * K + k0 + tx] = (__bf16)t[tx][ty + r];
}

// segments (cumulative blocks): cvt_pali 6144 | cvt_expe 1024 | wq_p 4096 | wk_p 512 |
// wv_p 512 | wq_e 2048 | wk_e 256 | wv_e 256 | wo_p 4096 | wo_e 2048  => 20992 total
__global__ __launch_bounds__(256) void prep_kernel(
    const float* __restrict__ pali, const float* __restrict__ expe,
    const float* __restrict__ wq_p, const float* __restrict__ wk_p, const float* __restrict__ wv_p,
    const float* __restrict__ wq_e, const float* __restrict__ wk_e, const float* __restrict__ wv_e,
    const float* __restrict__ wo_p, const float* __restrict__ wo_e,
    __bf16* __restrict__ palib, __bf16* __restrict__ expeb,
    __bf16* __restrict__ WqkvpT, __bf16* __restrict__ WqkveT,
    __bf16* __restrict__ WopT, __bf16* __restrict__ WoeT)
{
  __shared__ float t[32][33];
  const int bid = blockIdx.x, tid = threadIdx.x;
  if      (bid <  6144) do_cvt(pali, palib, bid * 256 + tid);
  else if (bid <  7168) do_cvt(expe, expeb, (bid - 6144) * 256 + tid);
  else if (bid < 11264) do_transpose(wq_p, WqkvpT,                       2048, 2048, bid - 7168,  tid, t);
  else if (bid < 11776) do_transpose(wk_p, WqkvpT + (size_t)2048 * 2048, 2048,  256, bid - 11264, tid, t);
  else if (bid < 12288) do_transpose(wv_p, WqkvpT + (size_t)2304 * 2048, 2048,  256, bid - 11776, tid, t);
  else if (bid < 14336) do_transpose(wq_e, WqkveT,                       1024, 2048, bid - 12288, tid, t);
  else if (bid < 14592) do_transpose(wk_e, WqkveT + (size_t)2048 * 1024, 1024,  256, bid - 14336, tid, t);
  else if (bid < 14848) do_transpose(wv_e, WqkveT + (size_t)2304 * 1024, 1024,  256, bid - 14592, tid, t);
  else if (bid < 18944) do_transpose(wo_p, WopT,                         2048, 2048, bid - 14848, tid, t);
  else                  do_transpose(wo_e, WoeT,                         2048, 1024, bid - 18944, tid, t);
}

// ======================= bf16 MFMA GEMM body (m97 structure) =======================
template <typename OutT>
__device__ __forceinline__ void gemm_body(
    const __bf16* __restrict__ A, const __bf16* __restrict__ Wt, OutT* __restrict__ C,
    int La, int K, int A_Ls, int A_off, int C_Ls, int C_off, int ldc,
    int m0, int n0, __bf16* As, __bf16* Bs, int tid)
{
  const int wave = tid >> 6, lane = tid & 63;
  const int lrow = lane >> 2;
  const int k8   = lane & 3;

  const __bf16 *ag0, *ag1;
  {
    int m_a0 = m0 + wave * 16 + lrow;
    int m_a1 = m_a0 + 64;
    int b0 = m_a0 / La, b1 = m_a1 / La;
    ag0 = A + (size_t)(b0 * A_Ls + A_off + m_a0 - b0 * La) * K + k8 * 8;
    ag1 = A + (size_t)(b1 * A_Ls + A_off + m_a1 - b1 * La) * K + k8 * 8;
  }
  const __bf16* bg0 = Wt + (size_t)(n0 + wave * 16 + lrow) * K + k8 * 8;
  const __bf16* bg1 = bg0 + (size_t)64 * K;
  __bf16* al0 = As + wave * 512;
  __bf16* al1 = As + (4 + wave) * 512;
  __bf16* bl0 = Bs + wave * 512;
  __bf16* bl1 = Bs + (4 + wave) * 512;

  const int wm = (wave & 1) * 64, wn = (wave >> 1) * 64;
  const int fr = lane & 15, quad = lane >> 4;

  f32x4 acc[4][4];
#pragma unroll
  for (int i = 0; i < 4; ++i)
#pragma unroll
    for (int j = 0; j < 4; ++j) acc[i][j] = (f32x4){0.f, 0.f, 0.f, 0.f};

  for (int kk = 0; kk < K; kk += 32) {
    gld_lds16(ag0 + kk, al0);
    gld_lds16(ag1 + kk, al1);
    gld_lds16(bg0 + kk, bl0);
    gld_lds16(bg1 + kk, bl1);
    __syncthreads();
    bf16x8 af[4], bfr[4];
#pragma unroll
    for (int mt = 0; mt < 4; ++mt)
      af[mt] = *(const bf16x8*)(As + (wm + mt * 16 + fr) * 32 + quad * 8);
#pragma unroll
    for (int nt = 0; nt < 4; ++nt)
      bfr[nt] = *(const bf16x8*)(Bs + (wn + nt * 16 + fr) * 32 + quad * 8);
#pragma unroll
    for (int mt = 0; mt < 4; ++mt)
#pragma unroll
      for (int nt = 0; nt < 4; ++nt)
        acc[mt][nt] = __builtin_amdgcn_mfma_f32_16x16x32_bf16(af[mt], bfr[nt], acc[mt][nt], 0, 0, 0);
    __syncthreads();
  }

#pragma unroll
  for (int mt = 0; mt < 4; ++mt) {
#pragma unroll
    for (int r = 0; r < 4; ++r) {
      int m = m0 + wm + mt * 16 + quad * 4 + r;
      int b = m / La;
      OutT* crow = C + (size_t)(b * C_Ls + C_off + m - b * La) * ldc + n0 + wn + fr;
#pragma unroll
      for (int nt = 0; nt < 4; ++nt) crow[nt * 16] = (OutT)acc[mt][nt][r];
    }
  }
}

// Merged QKV projection: blocks 0..479 pali (24x20 tiles), 480..639 expert (8x20). bf16 out.
__global__ __launch_bounds__(256) void gemm_qkv_kernel(
    const __bf16* __restrict__ palib, const __bf16* __restrict__ expeb,
    const __bf16* __restrict__ WqkvpT, const __bf16* __restrict__ WqkveT,
    __bf16* __restrict__ QKV)
{
  __shared__ __bf16 As[128 * 32];
  __shared__ __bf16 Bs[128 * 32];
  const int idx = blockIdx.x, tid = threadIdx.x;
  if (idx < 480) {
    gemm_body<__bf16>(palib, WqkvpT, QKV, 768, 2048, 768, 0, L_TOT, 0, LDQKV,
                      (idx / 20) * 128, (idx % 20) * 128, As, Bs, tid);
  } else {
    int j = idx - 480;
    gemm_body<__bf16>(expeb, WqkveT, QKV, 256, 1024, 256, 0, L_TOT, 768, LDQKV,
                      (j / 20) * 128, (j % 20) * 128, As, Bs, tid);
  }
}

// Merged output projection: blocks 0..383 pali (24x16), 384..447 expert (8x8). f32 out.
__global__ __launch_bounds__(256) void gemm_out_kernel(
    const __bf16* __restrict__ Ab, const __bf16* __restrict__ WopT,
    const __bf16* __restrict__ WoeT, float* __restrict__ out)
{
  __shared__ __bf16 As[128 * 32];
  __shared__ __bf16 Bs[128 * 32];
  const int idx = blockIdx.x, tid = threadIdx.x;
  if (idx < 384) {
    gemm_body<float>(Ab, WopT, out, 768, 2048, 1024, 0, 768, 0, 2048,
                     (idx / 16) * 128, (idx % 16) * 128, As, Bs, tid);
  } else {
    int j = idx - 384;
    gemm_body<float>(Ab, WoeT, out + (size_t)4 * 768 * 2048, 256, 2048, 1024, 768, 256, 0, 1024,
                     (j / 8) * 128, (j % 8) * 128, As, Bs, tid);
  }
}

// ======================= RoPE in place on bf16 QKV (Q heads 0..7, K head = 8) =======================
__global__ __launch_bounds__(256) void rope_kernel(
    __bf16* __restrict__ x, const int* __restrict__ pos)
{
  int idx = blockIdx.x * 256 + threadIdx.x;   // 4*1024*9*128
  int j = idx & 127;
  int t = idx >> 7;
  int hh = t % 9;
  int bl = t / 9;
  int b = bl >> 10;
  int l = bl & (L_TOT - 1);
  int col = (hh < 8) ? hh * HD : 2048;
  float p = (float)pos[b * L_TOT + l];
  float f = p * expf(-(float)j * (9.210340371976184f / 128.f));
  float s, c;
  sincosf(f, &s, &c);
  size_t base = (size_t)bl * LDQKV + col;
  float x1 = (float)x[base + j], x2 = (float)x[base + 128 + j];
  x[base + j]       = (__bf16)(x1 * c - x2 * s);
  x[base + 128 + j] = (__bf16)(x2 * c + x1 * s);
}

// V columns of bf16 QKV -> Vt bf16 (B,256,1024)
__global__ __launch_bounds__(256) void transpose_v_kernel(
    const __bf16* __restrict__ QKV, __bf16* __restrict__ Vt)
{
  __shared__ __bf16 t[32][33];
  const int b = blockIdx.z, d0 = blockIdx.x * 32, l0 = blockIdx.y * 32;
  const int tx = threadIdx.x & 31, ty = threadIdx.x >> 5;
#pragma unroll
  for (int r = 0; r < 32; r += 8)
    t[ty + r][tx] = QKV[(size_t)(b * L_TOT + l0 + ty + r) * LDQKV + 2304 + d0 + tx];
  __syncthreads();
#pragma unroll
  for (int r = 0; r < 32; r += 8)
    Vt[(size_t)(b * HD + d0 + ty + r) * L_TOT + l0 + tx] = t[tx][ty + r];
}

// ======================= MFMA flash attention (double-buffered, bf16 QKV) =======================
__global__ __launch_bounds__(256) void attn_mfma_kernel(
    const __bf16* __restrict__ QKV, const __bf16* __restrict__ Vt,
    const float* __restrict__ mask, __bf16* __restrict__ O)
{
  const int tid  = threadIdx.x;
  const int wave = tid >> 6, lane = tid & 63;
  const int m    = lane & 15, quad = lane >> 4;
  const int h = blockIdx.y, b = blockIdx.z;
  const int q0 = blockIdx.x * 64 + wave * 16;

  __shared__ __align__(16) __bf16 Ks[2][32 * 256];   // [buf][key][dim], group rotated by key
  __shared__ __align__(16) __bf16 Vs[2][256 * 32];   // [buf][dim][key], group rotated by (d>>1)&3
  __shared__ __align__(16) __bf16 Ps[4][16][40];

  // ---- Q A-fragments: direct bf16 16B loads. A[m][k=kf*32+quad*8+j] ----
  bf16x8 qf[8];
  {
    const __bf16* qrow = QKV + (size_t)(b * L_TOT + q0 + m) * LDQKV + h * HD + quad * 8;
#pragma unroll
    for (int f = 0; f < 8; ++f) qf[f] = *(const bf16x8*)(qrow + f * 32);
  }

  const int krow_l = lane >> 5;
  const int vd_l   = lane >> 2;
  const int vg_l   = lane & 3;

  size_t ksrc[4], vsrc[4];
#pragma unroll
  for (int i = 0; i < 4; ++i) {
    int c = wave * 4 + i;
    int r = 2 * c + krow_l;
    int colg = ((lane & 31) - r) & 31;
    ksrc[i] = (size_t)(b * L_TOT + r) * LDQKV + 2048 + colg * 8;   // K cols of QKV
    int d = c * 16 + vd_l;
    int gg = (vg_l - ((d >> 1) & 3)) & 3;
    vsrc[i] = ((size_t)(b * HD + d)) * L_TOT + gg * 8;
  }

  const float* mk = mask + (size_t)b * L_TOT * L_TOT + (size_t)(q0 + quad * 4) * L_TOT + m;

  f32x4 Oacc[16];
#pragma unroll
  for (int i = 0; i < 16; ++i) Oacc[i] = (f32x4){0.f, 0.f, 0.f, 0.f};
  float mrow[4] = {-1e30f, -1e30f, -1e30f, -1e30f};
  float lrow[4] = {0.f, 0.f, 0.f, 0.f};

#pragma unroll
  for (int i = 0; i < 4; ++i) {
    int c = wave * 4 + i;
    gld_lds16(QKV + ksrc[i], &Ks[0][c * 512]);
    gld_lds16(Vt + vsrc[i], &Vs[0][c * 512]);
  }
  float mcur[2][4];
#pragma unroll
  for (int nb = 0; nb < 2; ++nb)
#pragma unroll
    for (int r = 0; r < 4; ++r) mcur[nb][r] = mk[(size_t)r * L_TOT + nb * 16];

  for (int it = 0; it < 32; ++it) {
    const int kt = it * 32;
    const int buf = it & 1;
    __syncthreads();

    if (it + 1 < 32) {
#pragma unroll
      for (int i = 0; i < 4; ++i) {
        int c = wave * 4 + i;
        gld_lds16(QKV + ksrc[i] + (size_t)(kt + 32) * LDQKV, &Ks[buf ^ 1][c * 512]);
        gld_lds16(Vt + vsrc[i] + (kt + 32), &Vs[buf ^ 1][c * 512]);
      }
    }
    float mnext[2][4];
    if (it + 1 < 32) {
#pragma unroll
      for (int nb = 0; nb < 2; ++nb)
#pragma unroll
        for (int r = 0; r < 4; ++r)
          mnext[nb][r] = mk[(size_t)r * L_TOT + (kt + 32) + nb * 16];
    }

    f32x4 S[2];
#pragma unroll
    for (int nb = 0; nb < 2; ++nb) {
      int row = nb * 16 + m;
      f32x4 se = (f32x4){0.f, 0.f, 0.f, 0.f};
      f32x4 so = (f32x4){0.f, 0.f, 0.f, 0.f};
#pragma unroll
      for (int kf = 0; kf < 8; ++kf) {
        bf16x8 kf8 = *(const bf16x8*)(&Ks[buf][0] + row * 256 + (((kf << 2) + quad + row) & 31) * 8);
        if (kf & 1) so = __builtin_amdgcn_mfma_f32_16x16x32_bf16(qf[kf], kf8, so, 0, 0, 0);
        else        se = __builtin_amdgcn_mfma_f32_16x16x32_bf16(qf[kf], kf8, se, 0, 0, 0);
      }
      S[nb] = se + so;
    }
#pragma unroll
    for (int nb = 0; nb < 2; ++nb)
#pragma unroll
      for (int r = 0; r < 4; ++r)
        S[nb][r] = S[nb][r] * 0.0625f + mcur[nb][r];
    float mx[4];
#pragma unroll
    for (int r = 0; r < 4; ++r) mx[r] = fmaxf(S[0][r], S[1][r]);
#pragma unroll
    for (int off = 1; off < 16; off <<= 1)
#pragma unroll
      for (int r = 0; r < 4; ++r)
        mx[r] = fmaxf(mx[r], __shfl_xor(mx[r], off, 64));
    float al[4];
#pragma unroll
    for (int r = 0; r < 4; ++r) {
      float mn = fmaxf(mrow[r], mx[r]);
      al[r] = __expf(mrow[r] - mn);
      mrow[r] = mn;
    }
    float rs[4] = {0.f, 0.f, 0.f, 0.f};
#pragma unroll
    for (int nb = 0; nb < 2; ++nb)
#pragma unroll
      for (int r = 0; r < 4; ++r) {
        float p = __expf(S[nb][r] - mrow[r]);
        rs[r] += p;
        Ps[wave][quad * 4 + r][nb * 16 + m] = (__bf16)p;
      }
#pragma unroll
    for (int off = 1; off < 16; off <<= 1)
#pragma unroll
      for (int r = 0; r < 4; ++r)
        rs[r] += __shfl_xor(rs[r], off, 64);
#pragma unroll
    for (int r = 0; r < 4; ++r) lrow[r] = lrow[r] * al[r] + rs[r];
#pragma unroll
    for (int nb2 = 0; nb2 < 16; ++nb2)
#pragma unroll
      for (int r = 0; r < 4; ++r) Oacc[nb2][r] *= al[r];
    bf16x8 pf = *(const bf16x8*)&Ps[wave][m][quad * 8];
#pragma unroll
    for (int nb2 = 0; nb2 < 16; ++nb2) {
      int d = nb2 * 16 + m;
      bf16x8 vfrag = *(const bf16x8*)(&Vs[buf][0] + d * 32 + ((quad + ((d >> 1) & 3)) & 3) * 8);
      Oacc[nb2] = __builtin_amdgcn_mfma_f32_16x16x32_bf16(pf, vfrag, Oacc[nb2], 0, 0, 0);
    }
#pragma unroll
    for (int nb = 0; nb < 2; ++nb)
#pragma unroll
      for (int r = 0; r < 4; ++r) mcur[nb][r] = mnext[nb][r];
  }
  float invl[4];
#pragma unroll
  for (int r = 0; r < 4; ++r) invl[r] = 1.f / lrow[r];
  __bf16* orow = O + (size_t)(b * L_TOT + q0 + quad * 4) * 2048 + h * HD + m;
#pragma unroll
  for (int nb2 = 0; nb2 < 16; ++nb2)
#pragma unroll
    for (int r = 0; r < 4; ++r)
      orow[(size_t)r * 2048 + nb2 * 16] = (__bf16)(Oacc[nb2][r] * invl[r]);
}

extern "C" void kernel_launch(void* const* d_in, const int* in_sizes, int n_in,
                              void* d_out, int out_size, void* d_ws, size_t ws_size,
                              hipStream_t stream) {
  const float* pali = (const float*)d_in[0];
  const float* expe = (const float*)d_in[1];
  const int*   pos  = (const int*)d_in[2];
  const float* mask = (const float*)d_in[3];
  const float* wq_p = (const float*)d_in[5];
  const float* wk_p = (const float*)d_in[6];
  const float* wv_p = (const float*)d_in[7];
  const float* wo_p = (const float*)d_in[8];
  const float* wq_e = (const float*)d_in[9];
  const float* wk_e = (const float*)d_in[10];
  const float* wv_e = (const float*)d_in[11];
  const float* wo_e = (const float*)d_in[12];
  float* out = (float*)d_out;

  // Workspace (all bf16 except noted)
  __bf16* QKV    = (__bf16*)d_ws;                      // 4*1024*2560
  __bf16* Ab     = QKV + (size_t)4 * 1024 * 2560;      // 4*1024*2048
  __bf16* palib  = Ab + (size_t)4 * 1024 * 2048;       // 4*768*2048
  __bf16* expeb  = palib + (size_t)4 * 768 * 2048;     // 4*256*1024
  __bf16* Vt     = expeb + (size_t)4 * 256 * 1024;     // 4*256*1024
  __bf16* WqkvpT = Vt + (size_t)4 * 256 * 1024;        // 2560*2048
  __bf16* WqkveT = WqkvpT + (size_t)2560 * 2048;       // 2560*1024
  __bf16* WopT   = WqkveT + (size_t)2560 * 1024;       // 2048*2048
  __bf16* WoeT   = WopT + (size_t)2048 * 2048;         // 1024*2048

  dim3 blk(256);
  prep_kernel<<<20992, blk, 0, stream>>>(pali, expe, wq_p, wk_p, wv_p, wq_e, wk_e, wv_e,
                                         wo_p, wo_e, palib, expeb, WqkvpT, WqkveT, WopT, WoeT);
  gemm_qkv_kernel<<<640, blk, 0, stream>>>(palib, expeb, WqkvpT, WqkveT, QKV);
  rope_kernel<<<4 * 1024 * 9 * 128 / 256, blk, 0, stream>>>(QKV, pos);
  transpose_v_kernel<<<dim3(8, 32, 4), blk, 0, stream>>>(QKV, Vt);
  attn_mfma_kernel<<<dim3(16, 8, 4), blk, 0, stream>>>(QKV, Vt, mask, Ab);
  gemm_out_kernel<<<448, blk, 0, stream>>>(Ab, WopT, WoeT, out);
}